// Round 9
// baseline (1276.678 us; speedup 1.0000x reference)
//
#include <hip/hip_runtime.h>
#include <hip/hip_bf16.h>

#define Df 384
#define Hf 768
#define SCAN_CH 4096

typedef __bf16 bf16x8 __attribute__((ext_vector_type(8)));
typedef float f32x4 __attribute__((ext_vector_type(4)));

struct __attribute__((aligned(4))) U12 { unsigned int x, y, z; };

__device__ inline unsigned short f2bf(float f) {
    __hip_bfloat16 h = __float2bfloat16(f);
    return __builtin_bit_cast(unsigned short, h);
}
__device__ inline float bf2f(unsigned short u) {
    unsigned int v = ((unsigned int)u) << 16;
    return __builtin_bit_cast(float, v);
}
__device__ inline float lobf(unsigned int v) { return bf2f((unsigned short)(v & 0xffff)); }
__device__ inline float hibf(unsigned int v) { return bf2f((unsigned short)(v >> 16)); }
__device__ inline unsigned int pk2(float a, float b) {
    return (unsigned int)f2bf(a) | ((unsigned int)f2bf(b) << 16);
}
__device__ inline float gelu_(float v) {
    return 0.5f * v * (1.0f + erff(v * 0.70710678118654752f));
}
// direct global->LDS, 16B/lane; LDS dest is WAVE-UNIFORM base, HW adds lane*16.
__device__ inline void gload16(const void* g, void* l) {
    __builtin_amdgcn_global_load_lds(
        (const __attribute__((address_space(1))) unsigned int*)g,
        (__attribute__((address_space(3))) unsigned int*)l, 16, 0, 0);
}

// ---- BN column statistics ----
__global__ void bn_stats(const float* __restrict__ x, float* __restrict__ stats, int N) {
    int t = threadIdx.x;                 // 192 threads
    int c4 = (t % 96) * 4;
    int rs = t / 96;
    float s0 = 0, s1 = 0, s2 = 0, s3 = 0, q0 = 0, q1 = 0, q2 = 0, q3 = 0;
    for (int r = blockIdx.x * 2 + rs; r < N; r += gridDim.x * 2) {
        float4 v = *(const float4*)(x + (size_t)r * Df + c4);
        s0 += v.x; s1 += v.y; s2 += v.z; s3 += v.w;
        q0 += v.x * v.x; q1 += v.y * v.y; q2 += v.z * v.z; q3 += v.w * v.w;
    }
    unsafeAtomicAdd(&stats[c4 + 0], s0);
    unsafeAtomicAdd(&stats[c4 + 1], s1);
    unsafeAtomicAdd(&stats[c4 + 2], s2);
    unsafeAtomicAdd(&stats[c4 + 3], s3);
    unsafeAtomicAdd(&stats[Df + c4 + 0], q0);
    unsafeAtomicAdd(&stats[Df + c4 + 1], q1);
    unsafeAtomicAdd(&stats[Df + c4 + 2], q2);
    unsafeAtomicAdd(&stats[Df + c4 + 3], q3);
}

__global__ void bn_finalize(const float* __restrict__ stats,
                            const float* __restrict__ gamma,
                            const float* __restrict__ beta,
                            float* __restrict__ coef, int N) {
    int c = threadIdx.x; // 384
    float invN = 1.0f / (float)N;
    float mu = stats[c] * invN;
    float var = stats[Df + c] * invN - mu * mu;
    float rs = rsqrtf(var + 1e-5f);
    float a = gamma[c] * rs;
    coef[c] = a;
    coef[Df + c] = beta[c] - mu * a;
}

// ---- h = x*a + b  ->  bf16 ----
__global__ void h_kernel(const float* __restrict__ x, const float* __restrict__ coef,
                         unsigned short* __restrict__ hb, int tot8) {
    int i = blockIdx.x * 256 + threadIdx.x;
    if (i >= tot8) return;
    size_t base = (size_t)i * 8;
    int c = (int)(base % Df);
    float4 x0 = *(const float4*)(x + base);
    float4 x1 = *(const float4*)(x + base + 4);
    const float* a = coef + c;
    const float* b = coef + Df + c;
    uint4 o;
    o.x = pk2(x0.x * a[0] + b[0], x0.y * a[1] + b[1]);
    o.y = pk2(x0.z * a[2] + b[2], x0.w * a[3] + b[3]);
    o.z = pk2(x1.x * a[4] + b[4], x1.y * a[5] + b[5]);
    o.w = pk2(x1.z * a[6] + b[6], x1.w * a[7] + b[7]);
    *(uint4*)(hb + base) = o;
}

// ---- plain f32 -> bf16 cast (for ea) ----
__global__ void cast_bf16(const float* __restrict__ src, unsigned short* __restrict__ dst, int tot8) {
    int i = blockIdx.x * 256 + threadIdx.x;
    if (i >= tot8) return;
    size_t base = (size_t)i * 8;
    float4 x0 = *(const float4*)(src + base);
    float4 x1 = *(const float4*)(src + base + 4);
    uint4 o;
    o.x = pk2(x0.x, x0.y); o.y = pk2(x0.z, x0.w);
    o.z = pk2(x1.x, x1.y); o.w = pk2(x1.z, x1.w);
    *(uint4*)(dst + base) = o;
}

// ---- weight transpose + cast: W[K][Nc] f32 -> Wt[Nc][K] bf16 ----
__global__ void wtrans(const float* __restrict__ Wsrc, unsigned short* __restrict__ Wdst,
                       int K, int Nc) {
    int idx = blockIdx.x * 256 + threadIdx.x;
    if (idx >= K * Nc) return;
    int k = idx / Nc, n = idx % Nc;
    Wdst[(size_t)n * K + k] = f2bf(Wsrc[idx]);
}

// ---- CSR build ----
__global__ void degree_k(const int* __restrict__ dst, int* __restrict__ deg, int E) {
    int e = blockIdx.x * 256 + threadIdx.x;
    if (e < E) atomicAdd(&deg[dst[e]], 1);
}

__global__ void scan1(const int* __restrict__ deg, int* __restrict__ off,
                      int* __restrict__ sums, int N) {
    __shared__ int ts[256];
    int t = threadIdx.x;
    int base = blockIdx.x * SCAN_CH + t * 16;
    int v[16];
    int s = 0;
    for (int j = 0; j < 16; j++) {
        int idx = base + j;
        int d = (idx < N) ? deg[idx] : 0;
        v[j] = s;
        s += d;
    }
    ts[t] = s;
    __syncthreads();
    for (int o = 1; o < 256; o <<= 1) {
        int add = (t >= o) ? ts[t - o] : 0;
        __syncthreads();
        ts[t] += add;
        __syncthreads();
    }
    int pre = t ? ts[t - 1] : 0;
    for (int j = 0; j < 16; j++) {
        int idx = base + j;
        if (idx < N) off[idx] = pre + v[j];
    }
    if (t == 255) sums[blockIdx.x] = ts[255];
}

__global__ void scan2(int* __restrict__ sums, int nb) {
    int acc = 0;
    for (int b = 0; b < nb; b++) { int v = sums[b]; sums[b] = acc; acc += v; }
    sums[nb] = acc;
}

__global__ void scan3(int* __restrict__ off, const int* __restrict__ sums, int N, int nb) {
    int idx = blockIdx.x * 256 + threadIdx.x;
    if (idx < N) off[idx] += sums[idx / SCAN_CH];
    else if (idx == N) off[N] = sums[nb];
}

// fill: pose[e] = CSR slot of edge e; srcp[slot] = src node of that edge
__global__ void fill_k(const int* __restrict__ dst, const int* __restrict__ src,
                       int* __restrict__ cursor, int* __restrict__ srcp,
                       int* __restrict__ pose, int E) {
    int e = blockIdx.x * 256 + threadIdx.x;
    if (e >= E) return;
    int pos = atomicAdd(&cursor[dst[e]], 1);
    srcp[pos] = src[e];
    pose[e] = pos;
}

// ---- gather-reduce: z[i] = (1+eps)*h[i] + sum relu(msgl[p] + h[srcp[p]]) ----
__global__ __launch_bounds__(256) void aggregate(
    const unsigned short* __restrict__ msgl, const unsigned short* __restrict__ hb,
    const int* __restrict__ off, const int* __restrict__ srcp,
    const float* __restrict__ epsp,
    unsigned short* __restrict__ zb, int N) {
    int lane = threadIdx.x & 63;
    int wid = threadIdx.x >> 6;
    int nwaves = gridDim.x * 4;
    float s1p = 1.0f + epsp[0];
    int loff = lane * 6;
    for (int i = blockIdx.x * 4 + wid; i < N; i += nwaves) {
        int o0 = off[i], o1 = off[i + 1];
        float a0 = 0, a1 = 0, a2 = 0, a3 = 0, a4 = 0, a5 = 0;
        for (int p = o0; p < o1; ++p) {
            int s = srcp[p];
            U12 mv = *(const U12*)(msgl + (size_t)p * Df + loff);
            U12 hv = *(const U12*)(hb + (size_t)s * Df + loff);
            a0 += fmaxf(lobf(mv.x) + lobf(hv.x), 0.f);
            a1 += fmaxf(hibf(mv.x) + hibf(hv.x), 0.f);
            a2 += fmaxf(lobf(mv.y) + lobf(hv.y), 0.f);
            a3 += fmaxf(hibf(mv.y) + hibf(hv.y), 0.f);
            a4 += fmaxf(lobf(mv.z) + lobf(hv.z), 0.f);
            a5 += fmaxf(hibf(mv.z) + hibf(hv.z), 0.f);
        }
        U12 hv = *(const U12*)(hb + (size_t)i * Df + loff);
        U12 o;
        o.x = pk2(s1p * lobf(hv.x) + a0, s1p * hibf(hv.x) + a1);
        o.y = pk2(s1p * lobf(hv.y) + a2, s1p * hibf(hv.y) + a3);
        o.z = pk2(s1p * lobf(hv.z) + a4, s1p * hibf(hv.z) + a5);
        *(U12*)(zb + (size_t)i * Df + loff) = o;
    }
}

// ---- 8-phase GEMM (m201 template port): C = A @ Bt^T (+bias + epilogue) ----
// BM=256, BN=192, BK=64 (2 k-halves). 8 waves (2M x 4N), wave out = 128x48,
// acc[8][3] f32x4. LDS = 2 tiles x {A 32K(2 k-halves) + B 24K} = 112KB.
// Per K-tile 4 phases: {ds_read frag subtile || stage 1 half-tile via
// global_load_lds || s_barrier || lgkmcnt(0) || setprio MFMA || s_barrier}.
// Stage targets = the half that died in the previous phase; one counted
// s_waitcnt vmcnt(6) per K-tile (3 half-tiles x 2 loads in flight).
// Swizzle: 16B segment XOR (row>>1)&3 on BOTH sides -> 2-way banks (free).
// EPI 1: bf16(gelu(acc+bias)); EPI 2: xres + gelu(acc+bias) (f32);
// EPI 3: outb[pose[row]] = bf16(acc+bias)
template <int NT, int EPI>
__global__ __launch_bounds__(512, 1) void gemm8p(
    const unsigned short* __restrict__ Ab, const unsigned short* __restrict__ Bt,
    const float* __restrict__ bias, int M, int ncols,
    const int* __restrict__ pose,
    unsigned short* __restrict__ outb,
    const float* __restrict__ xres, float* __restrict__ outf, int ldo) {
    constexpr int K = NT * 64;
    __shared__ __align__(16) unsigned short AS[2 * 2 * 256 * 32]; // [buf][khalf][256r][32k]
    __shared__ __align__(16) unsigned short BS[2 * 2 * 192 * 32]; // [buf][khalf][192r][32k]

    const int t = threadIdx.x;
    // m204 bijective XCD swizzle, col-block fastest within an XCD chunk
    const int nwg = gridDim.x;
    const int orig = blockIdx.x;
    const int xcd = orig & 7;
    const int q = nwg >> 3, r = nwg & 7;
    const int wgid = (xcd < r ? xcd * (q + 1) : r * (q + 1) + (xcd - r) * q) + (orig >> 3);
    const int pp = wgid / ncols;
    const int m0 = pp * 256;
    const int n0 = (wgid - pp * ncols) * 192;

    const int lane = t & 63;
    const int wid = t >> 6;
    const int fr = lane & 15;
    const int kg = lane >> 4;
    const int wm = wid >> 2;       // 0..1 (128-row half)
    const int wn = wid & 3;        // 0..3 (48-col slice)
    const int segw = ((lane & 3) ^ ((lane >> 3) & 3)) << 3;  // staging src k-seg (elems)
    const int rsw = (kg ^ ((fr >> 1) & 3)) << 3;             // frag-read k-seg (elems)

    f32x4 acc[8][3];
#pragma unroll
    for (int i = 0; i < 8; i++)
#pragma unroll
        for (int j = 0; j < 3; j++) acc[i][j] = (f32x4){0.f, 0.f, 0.f, 0.f};

    // ---- half-tile staging (2 x gload16 each; dest wave-uniform) ----
#define STG_AH(tt, kh) do {                                                     \
        const int bb_ = ((tt) & 1) * 2 + (kh);                                  \
        _Pragma("unroll")                                                       \
        for (int c_ = 0; c_ < 2; c_++) {                                        \
            int row_ = c_ * 128 + wid * 16 + (lane >> 2);                       \
            int gr_ = m0 + row_; if (gr_ >= M) gr_ = M - 1;                     \
            gload16(Ab + (size_t)gr_ * K + (tt) * 64 + (kh) * 32 + segw,        \
                    &AS[(bb_ * 256 + c_ * 128 + wid * 16) * 32]);               \
        } } while (0)
#define STG_BH(tt, kh) do {                                                     \
        const int bb_ = ((tt) & 1) * 2 + (kh);                                  \
        _Pragma("unroll")                                                       \
        for (int c_ = 0; c_ < 2; c_++) {                                        \
            int row_ = c_ * 64 + wid * 16 + (lane >> 2);                        \
            gload16(Bt + (size_t)(n0 + row_) * K + (tt) * 64 + (kh) * 32 + segw,\
                    &BS[(bb_ * 192 + c_ * 64 + wid * 16) * 32]);                \
        } } while (0)

    // prologue: tile0 fully + tile1 {Ah0,Bh0,Ah1}; Bh1(1) comes at t0.P1
    STG_AH(0, 0); STG_BH(0, 0); STG_AH(0, 1); STG_BH(0, 1);
    STG_AH(1, 0); STG_BH(1, 0); STG_AH(1, 1);
    asm volatile("s_waitcnt vmcnt(6)" ::: "memory");   // tile 0 resident
    __builtin_amdgcn_s_barrier();

    for (int kt = 0; kt < NT; ++kt) {
        const int b = kt & 1;
        const unsigned short* Ah0 = &AS[(b * 2 + 0) * 256 * 32];
        const unsigned short* Ah1 = &AS[(b * 2 + 1) * 256 * 32];
        const unsigned short* Bh0 = &BS[(b * 2 + 0) * 192 * 32];
        const unsigned short* Bh1 = &BS[(b * 2 + 1) * 192 * 32];
        bf16x8 a[8], bf0, bf1, bf2;

        // ---------- P1: k-half 0, cols j0,j1 ----------
#pragma unroll
        for (int i = 0; i < 8; i++)
            a[i] = *(const bf16x8*)&Ah0[(wm * 128 + i * 16 + fr) * 32 + rsw];
        bf0 = *(const bf16x8*)&Bh0[(wn * 48 + 0 + fr) * 32 + rsw];
        bf1 = *(const bf16x8*)&Bh0[(wn * 48 + 16 + fr) * 32 + rsw];
        if (kt + 1 < NT) STG_BH(kt + 1, 1);
        __builtin_amdgcn_s_barrier();
        asm volatile("s_waitcnt lgkmcnt(0)" ::: "memory");
        __builtin_amdgcn_sched_barrier(0);
        __builtin_amdgcn_s_setprio(1);
#pragma unroll
        for (int i = 0; i < 8; i++) {
            acc[i][0] = __builtin_amdgcn_mfma_f32_16x16x32_bf16(a[i], bf0, acc[i][0], 0, 0, 0);
            acc[i][1] = __builtin_amdgcn_mfma_f32_16x16x32_bf16(a[i], bf1, acc[i][1], 0, 0, 0);
        }
        __builtin_amdgcn_s_setprio(0);
        __builtin_amdgcn_s_barrier();

        // ---------- P2: k-half 0, col j2 (Ah0 died after P1) ----------
        bf2 = *(const bf16x8*)&Bh0[(wn * 48 + 32 + fr) * 32 + rsw];
        if (kt + 2 < NT) STG_AH(kt + 2, 0);
        __builtin_amdgcn_s_barrier();
        asm volatile("s_waitcnt lgkmcnt(0)" ::: "memory");
        __builtin_amdgcn_sched_barrier(0);
        __builtin_amdgcn_s_setprio(1);
#pragma unroll
        for (int i = 0; i < 8; i++)
            acc[i][2] = __builtin_amdgcn_mfma_f32_16x16x32_bf16(a[i], bf2, acc[i][2], 0, 0, 0);
        __builtin_amdgcn_s_setprio(0);
        __builtin_amdgcn_s_barrier();

        // ---------- P3: k-half 1, cols j0,j1 (Bh0 died after P2) ----------
#pragma unroll
        for (int i = 0; i < 8; i++)
            a[i] = *(const bf16x8*)&Ah1[(wm * 128 + i * 16 + fr) * 32 + rsw];
        bf0 = *(const bf16x8*)&Bh1[(wn * 48 + 0 + fr) * 32 + rsw];
        bf1 = *(const bf16x8*)&Bh1[(wn * 48 + 16 + fr) * 32 + rsw];
        if (kt + 2 < NT) STG_BH(kt + 2, 0);
        __builtin_amdgcn_s_barrier();
        asm volatile("s_waitcnt lgkmcnt(0)" ::: "memory");
        __builtin_amdgcn_sched_barrier(0);
        __builtin_amdgcn_s_setprio(1);
#pragma unroll
        for (int i = 0; i < 8; i++) {
            acc[i][0] = __builtin_amdgcn_mfma_f32_16x16x32_bf16(a[i], bf0, acc[i][0], 0, 0, 0);
            acc[i][1] = __builtin_amdgcn_mfma_f32_16x16x32_bf16(a[i], bf1, acc[i][1], 0, 0, 0);
        }
        __builtin_amdgcn_s_setprio(0);
        __builtin_amdgcn_s_barrier();

        // ---------- P4: k-half 1, col j2 (Ah1 died after P3) ----------
        bf2 = *(const bf16x8*)&Bh1[(wn * 48 + 32 + fr) * 32 + rsw];
        if (kt + 2 < NT) STG_AH(kt + 2, 1);
        __builtin_amdgcn_s_barrier();
        asm volatile("s_waitcnt lgkmcnt(0)" ::: "memory");
        __builtin_amdgcn_sched_barrier(0);
        __builtin_amdgcn_s_setprio(1);
#pragma unroll
        for (int i = 0; i < 8; i++)
            acc[i][2] = __builtin_amdgcn_mfma_f32_16x16x32_bf16(a[i], bf2, acc[i][2], 0, 0, 0);
        __builtin_amdgcn_s_setprio(0);
        // tile-boundary counted wait: next tile's 4 halves must be resident;
        // allow only this tile's P2/P3/P4 stages (3 halves = 6 loads) in flight.
        if (kt + 1 < NT) {
            if (kt + 2 < NT) asm volatile("s_waitcnt vmcnt(6)" ::: "memory");
            else             asm volatile("s_waitcnt vmcnt(0)" ::: "memory");
        }
        __builtin_amdgcn_s_barrier();
    }
#undef STG_AH
#undef STG_BH

    float bi[3];
#pragma unroll
    for (int j = 0; j < 3; j++) bi[j] = bias[n0 + wn * 48 + j * 16 + fr];

    const int kg4 = kg * 4;
#pragma unroll
    for (int i = 0; i < 8; i++) {
        const int rb = m0 + wm * 128 + i * 16 + kg4;
#pragma unroll
        for (int j = 0; j < 3; j++) {
            const int c = n0 + wn * 48 + j * 16 + fr;
#pragma unroll
            for (int rr = 0; rr < 4; rr++) {
                const int row = rb + rr;
                if (row < M) {
                    float v = acc[i][j][rr] + bi[j];
                    if (EPI == 1) {
                        outb[(size_t)row * ldo + c] = f2bf(gelu_(v));
                    } else if (EPI == 2) {
                        size_t o = (size_t)row * ldo + c;
                        outf[o] = xres[o] + gelu_(v);
                    } else {
                        outb[(size_t)pose[row] * ldo + c] = f2bf(v);
                    }
                }
            }
        }
    }
}

extern "C" void kernel_launch(void* const* d_in, const int* in_sizes, int n_in,
                              void* d_out, int out_size, void* d_ws, size_t ws_size,
                              hipStream_t stream) {
    const float* x = (const float*)d_in[0];
    const float* ea = (const float*)d_in[1];
    const float* gamma = (const float*)d_in[2];
    const float* beta = (const float*)d_in[3];
    const float* epsp = (const float*)d_in[4];
    const float* W_edge = (const float*)d_in[5];
    const float* b_edge = (const float*)d_in[6];
    const float* W1 = (const float*)d_in[7];
    const float* b1 = (const float*)d_in[8];
    const float* W2 = (const float*)d_in[9];
    const float* b2 = (const float*)d_in[10];
    const int* eidx = (const int*)d_in[11];
    float* out = (float*)d_out;
    const int N = in_sizes[0] / Df;
    const int E = in_sizes[1] / Df;
    const int* esrc = eidx;
    const int* edst = eidx + E;

    char* w = (char*)d_ws;
    size_t off_ = 0;
    auto alloc = [&](size_t bytes) { char* p = w + off_; off_ += (bytes + 255) & ~(size_t)255; return p; };
    float* stats = (float*)alloc(2 * Df * sizeof(float));
    float* coef = (float*)alloc(2 * Df * sizeof(float));
    unsigned short* hb = (unsigned short*)alloc((size_t)N * Df * 2);
    unsigned short* zb = (unsigned short*)alloc((size_t)N * Df * 2);
    unsigned short* tb = (unsigned short*)alloc((size_t)N * Hf * 2);   // also hosts eab (dead before GEMM1)
    unsigned short* WeT = (unsigned short*)alloc((size_t)Df * Df * 2);
    unsigned short* W1T = (unsigned short*)alloc((size_t)Df * Hf * 2);
    unsigned short* W2T = (unsigned short*)alloc((size_t)Hf * Df * 2);
    int* deg = (int*)alloc((size_t)(N + 1) * 4);      // reused as fill cursor
    int* offs = (int*)alloc((size_t)(N + 1) * 4);
    int* srcp = (int*)alloc((size_t)E * 4);
    int* pose = (int*)alloc((size_t)E * 4);
    int* sums = (int*)alloc(64 * 4);
    size_t msgl_bytes = (size_t)E * Df * 2;
    unsigned short* msgl;
    if (off_ + msgl_bytes <= ws_size) msgl = (unsigned short*)alloc(msgl_bytes);
    else msgl = (unsigned short*)d_out;   // dead until final GEMM writes it
    unsigned short* eab = tb;             // ea as bf16, aliased onto tb
    (void)n_in; (void)out_size;

    hipMemsetAsync(stats, 0, 2 * Df * sizeof(float), stream);
    hipMemsetAsync(deg, 0, (size_t)N * 4, stream);

    // BN + h
    bn_stats<<<1024, 192, 0, stream>>>(x, stats, N);
    bn_finalize<<<1, Df, 0, stream>>>(stats, gamma, beta, coef, N);
    int tot8 = N * Df / 8;
    h_kernel<<<(tot8 + 255) / 256, 256, 0, stream>>>(x, coef, hb, tot8);

    // ea -> bf16
    int etot8 = E * Df / 8;
    cast_bf16<<<(etot8 + 255) / 256, 256, 0, stream>>>(ea, eab, etot8);

    // weights
    wtrans<<<(Df * Df + 255) / 256, 256, 0, stream>>>(W_edge, WeT, Df, Df);
    wtrans<<<(Df * Hf + 255) / 256, 256, 0, stream>>>(W1, W1T, Df, Hf);
    wtrans<<<(Hf * Df + 255) / 256, 256, 0, stream>>>(W2, W2T, Hf, Df);

    // CSR by dst
    int nb = (N + SCAN_CH - 1) / SCAN_CH;
    degree_k<<<(E + 255) / 256, 256, 0, stream>>>(edst, deg, E);
    scan1<<<nb, 256, 0, stream>>>(deg, offs, sums, N);
    scan2<<<1, 1, 0, stream>>>(sums, nb);
    scan3<<<(N + 256) / 256, 256, 0, stream>>>(offs, sums, N, nb);
    hipMemcpyAsync(deg, offs, (size_t)N * 4, hipMemcpyDeviceToDevice, stream);
    fill_k<<<(E + 255) / 256, 256, 0, stream>>>(edst, esrc, deg, srcp, pose, E);

    // edge linear: msgl[pose[e]] = eab[e] @ We^T + b_edge  (bf16, CSR-ordered)
    int ep = (E + 255) / 256;
    gemm8p<6, 3><<<dim3(ep * (Df / 192)), 512, 0, stream>>>(
        eab, WeT, b_edge, E, Df / 192, pose, msgl, nullptr, nullptr, Df);

    // gather-reduce -> z (bf16)
    aggregate<<<2048, 256, 0, stream>>>(msgl, hb, offs, srcp, epsp, zb, N);

    // MLP
    int np = (N + 255) / 256;
    gemm8p<6, 1><<<dim3(np * (Hf / 192)), 512, 0, stream>>>(
        zb, W1T, b1, N, Hf / 192, nullptr, tb, nullptr, nullptr, Hf);
    gemm8p<12, 2><<<dim3(np * (Df / 192)), 512, 0, stream>>>(
        tb, W2T, b2, N, Df / 192, nullptr, nullptr, x, out, Df);
}

// Round 10
// 1151.895 us; speedup vs baseline: 1.1083x; 1.1083x over previous
//
#include <hip/hip_runtime.h>
#include <hip/hip_bf16.h>

#define Df 384
#define Hf 768
#define SCAN_CH 4096

typedef __bf16 bf16x8 __attribute__((ext_vector_type(8)));
typedef float f32x4 __attribute__((ext_vector_type(4)));

struct __attribute__((aligned(4))) U12 { unsigned int x, y, z; };

__device__ inline unsigned short f2bf(float f) {
    __hip_bfloat16 h = __float2bfloat16(f);
    return __builtin_bit_cast(unsigned short, h);
}
__device__ inline float bf2f(unsigned short u) {
    unsigned int v = ((unsigned int)u) << 16;
    return __builtin_bit_cast(float, v);
}
__device__ inline float lobf(unsigned int v) { return bf2f((unsigned short)(v & 0xffff)); }
__device__ inline float hibf(unsigned int v) { return bf2f((unsigned short)(v >> 16)); }
__device__ inline unsigned int pk2(float a, float b) {
    return (unsigned int)f2bf(a) | ((unsigned int)f2bf(b) << 16);
}
__device__ inline float gelu_(float v) {
    return 0.5f * v * (1.0f + erff(v * 0.70710678118654752f));
}
// direct global->LDS, 16B/lane; LDS dest is WAVE-UNIFORM base, HW adds lane*16.
__device__ inline void gload16(const void* g, void* l) {
    __builtin_amdgcn_global_load_lds(
        (const __attribute__((address_space(1))) unsigned int*)g,
        (__attribute__((address_space(3))) unsigned int*)l, 16, 0, 0);
}

// ---- BN column statistics ----
__global__ void bn_stats(const float* __restrict__ x, float* __restrict__ stats, int N) {
    int t = threadIdx.x;                 // 192 threads
    int c4 = (t % 96) * 4;
    int rs = t / 96;
    float s0 = 0, s1 = 0, s2 = 0, s3 = 0, q0 = 0, q1 = 0, q2 = 0, q3 = 0;
    for (int r = blockIdx.x * 2 + rs; r < N; r += gridDim.x * 2) {
        float4 v = *(const float4*)(x + (size_t)r * Df + c4);
        s0 += v.x; s1 += v.y; s2 += v.z; s3 += v.w;
        q0 += v.x * v.x; q1 += v.y * v.y; q2 += v.z * v.z; q3 += v.w * v.w;
    }
    unsafeAtomicAdd(&stats[c4 + 0], s0);
    unsafeAtomicAdd(&stats[c4 + 1], s1);
    unsafeAtomicAdd(&stats[c4 + 2], s2);
    unsafeAtomicAdd(&stats[c4 + 3], s3);
    unsafeAtomicAdd(&stats[Df + c4 + 0], q0);
    unsafeAtomicAdd(&stats[Df + c4 + 1], q1);
    unsafeAtomicAdd(&stats[Df + c4 + 2], q2);
    unsafeAtomicAdd(&stats[Df + c4 + 3], q3);
}

__global__ void bn_finalize(const float* __restrict__ stats,
                            const float* __restrict__ gamma,
                            const float* __restrict__ beta,
                            float* __restrict__ coef, int N) {
    int c = threadIdx.x; // 384
    float invN = 1.0f / (float)N;
    float mu = stats[c] * invN;
    float var = stats[Df + c] * invN - mu * mu;
    float rs = rsqrtf(var + 1e-5f);
    float a = gamma[c] * rs;
    coef[c] = a;
    coef[Df + c] = beta[c] - mu * a;
}

// ---- h = x*a + b  ->  bf16 ----
__global__ void h_kernel(const float* __restrict__ x, const float* __restrict__ coef,
                         unsigned short* __restrict__ hb, int tot8) {
    int i = blockIdx.x * 256 + threadIdx.x;
    if (i >= tot8) return;
    size_t base = (size_t)i * 8;
    int c = (int)(base % Df);
    float4 x0 = *(const float4*)(x + base);
    float4 x1 = *(const float4*)(x + base + 4);
    const float* a = coef + c;
    const float* b = coef + Df + c;
    uint4 o;
    o.x = pk2(x0.x * a[0] + b[0], x0.y * a[1] + b[1]);
    o.y = pk2(x0.z * a[2] + b[2], x0.w * a[3] + b[3]);
    o.z = pk2(x1.x * a[4] + b[4], x1.y * a[5] + b[5]);
    o.w = pk2(x1.z * a[6] + b[6], x1.w * a[7] + b[7]);
    *(uint4*)(hb + base) = o;
}

// ---- plain f32 -> bf16 cast (for ea) ----
__global__ void cast_bf16(const float* __restrict__ src, unsigned short* __restrict__ dst, int tot8) {
    int i = blockIdx.x * 256 + threadIdx.x;
    if (i >= tot8) return;
    size_t base = (size_t)i * 8;
    float4 x0 = *(const float4*)(src + base);
    float4 x1 = *(const float4*)(src + base + 4);
    uint4 o;
    o.x = pk2(x0.x, x0.y); o.y = pk2(x0.z, x0.w);
    o.z = pk2(x1.x, x1.y); o.w = pk2(x1.z, x1.w);
    *(uint4*)(dst + base) = o;
}

// ---- weight transpose + cast: W[K][Nc] f32 -> Wt[Nc][K] bf16 ----
__global__ void wtrans(const float* __restrict__ Wsrc, unsigned short* __restrict__ Wdst,
                       int K, int Nc) {
    int idx = blockIdx.x * 256 + threadIdx.x;
    if (idx >= K * Nc) return;
    int k = idx / Nc, n = idx % Nc;
    Wdst[(size_t)n * K + k] = f2bf(Wsrc[idx]);
}

// ---- CSR build ----
__global__ void degree_k(const int* __restrict__ dst, int* __restrict__ deg, int E) {
    int e = blockIdx.x * 256 + threadIdx.x;
    if (e < E) atomicAdd(&deg[dst[e]], 1);
}

__global__ void scan1(const int* __restrict__ deg, int* __restrict__ off,
                      int* __restrict__ sums, int N) {
    __shared__ int ts[256];
    int t = threadIdx.x;
    int base = blockIdx.x * SCAN_CH + t * 16;
    int v[16];
    int s = 0;
    for (int j = 0; j < 16; j++) {
        int idx = base + j;
        int d = (idx < N) ? deg[idx] : 0;
        v[j] = s;
        s += d;
    }
    ts[t] = s;
    __syncthreads();
    for (int o = 1; o < 256; o <<= 1) {
        int add = (t >= o) ? ts[t - o] : 0;
        __syncthreads();
        ts[t] += add;
        __syncthreads();
    }
    int pre = t ? ts[t - 1] : 0;
    for (int j = 0; j < 16; j++) {
        int idx = base + j;
        if (idx < N) off[idx] = pre + v[j];
    }
    if (t == 255) sums[blockIdx.x] = ts[255];
}

__global__ void scan2(int* __restrict__ sums, int nb) {
    int acc = 0;
    for (int b = 0; b < nb; b++) { int v = sums[b]; sums[b] = acc; acc += v; }
    sums[nb] = acc;
}

__global__ void scan3(int* __restrict__ off, const int* __restrict__ sums, int N, int nb) {
    int idx = blockIdx.x * 256 + threadIdx.x;
    if (idx < N) off[idx] += sums[idx / SCAN_CH];
    else if (idx == N) off[N] = sums[nb];
}

// fill: pose[e] = CSR slot of edge e; srcp[slot] = src node of that edge
__global__ void fill_k(const int* __restrict__ dst, const int* __restrict__ src,
                       int* __restrict__ cursor, int* __restrict__ srcp,
                       int* __restrict__ pose, int E) {
    int e = blockIdx.x * 256 + threadIdx.x;
    if (e >= E) return;
    int pos = atomicAdd(&cursor[dst[e]], 1);
    srcp[pos] = src[e];
    pose[e] = pos;
}

// ---- gather-reduce: z[i] = (1+eps)*h[i] + sum relu(msgl[p] + h[srcp[p]]) ----
__global__ __launch_bounds__(256) void aggregate(
    const unsigned short* __restrict__ msgl, const unsigned short* __restrict__ hb,
    const int* __restrict__ off, const int* __restrict__ srcp,
    const float* __restrict__ epsp,
    unsigned short* __restrict__ zb, int N) {
    int lane = threadIdx.x & 63;
    int wid = threadIdx.x >> 6;
    int nwaves = gridDim.x * 4;
    float s1p = 1.0f + epsp[0];
    int loff = lane * 6;
    for (int i = blockIdx.x * 4 + wid; i < N; i += nwaves) {
        int o0 = off[i], o1 = off[i + 1];
        float a0 = 0, a1 = 0, a2 = 0, a3 = 0, a4 = 0, a5 = 0;
        for (int p = o0; p < o1; ++p) {
            int s = srcp[p];
            U12 mv = *(const U12*)(msgl + (size_t)p * Df + loff);
            U12 hv = *(const U12*)(hb + (size_t)s * Df + loff);
            a0 += fmaxf(lobf(mv.x) + lobf(hv.x), 0.f);
            a1 += fmaxf(hibf(mv.x) + hibf(hv.x), 0.f);
            a2 += fmaxf(lobf(mv.y) + lobf(hv.y), 0.f);
            a3 += fmaxf(hibf(mv.y) + hibf(hv.y), 0.f);
            a4 += fmaxf(lobf(mv.z) + lobf(hv.z), 0.f);
            a5 += fmaxf(hibf(mv.z) + hibf(hv.z), 0.f);
        }
        U12 hv = *(const U12*)(hb + (size_t)i * Df + loff);
        U12 o;
        o.x = pk2(s1p * lobf(hv.x) + a0, s1p * hibf(hv.x) + a1);
        o.y = pk2(s1p * lobf(hv.y) + a2, s1p * hibf(hv.y) + a3);
        o.z = pk2(s1p * lobf(hv.z) + a4, s1p * hibf(hv.z) + a5);
        *(U12*)(zb + (size_t)i * Df + loff) = o;
    }
}

// ---- Fused MLP: out = x + gelu( gelu(z@W1+b1) @ W2 + b2 )  ----
// Block = 64 rows, 8 waves. z-tile (49KB) staged to LDS via gload_lds with
// pre-swizzled source (chunk pos ^= row&7); t (64x768 bf16, 98KB) lives in
// LDS with the same XOR swizzle. W1T/W2T (1.2MB total) are read as
// B-fragments DIRECTLY from global -- L2-resident, shared by every block.
// Pass1: wave w computes t cols [w*96, w*96+96); pass2: out cols [w*48,+48).
__global__ __launch_bounds__(512, 1) void mlp_fused(
    const unsigned short* __restrict__ zb, const unsigned short* __restrict__ W1T,
    const float* __restrict__ b1, const unsigned short* __restrict__ W2T,
    const float* __restrict__ b2, const float* __restrict__ x,
    float* __restrict__ out, int M) {
    __shared__ __align__(16) unsigned short zS[64 * 384];   // 49152 B
    __shared__ __align__(16) unsigned short tS[64 * 768];   // 98304 B

    const int t = threadIdx.x;
    const int lane = t & 63;
    const int wid = t >> 6;
    const int fr = lane & 15;
    const int kg = lane >> 4;
    const int kg4 = kg * 4;
    const int m0 = blockIdx.x * 64;

    // ---- stage z tile: linear LDS dest, pre-swizzled global source ----
    // chunk c = (wid*6+si)*64 + lane; row = c/48, pos = c%48 (16B units)
#pragma unroll
    for (int si = 0; si < 6; si++) {
        int c = (wid * 6 + si) * 64 + lane;
        int row = c / 48;
        int pos = c - row * 48;
        int gr = m0 + row; if (gr >= M) gr = M - 1;
        gload16(zb + (size_t)gr * Df + ((pos ^ (row & 7)) << 3),
                &zS[(wid * 6 + si) * 512]);
    }
    asm volatile("s_waitcnt vmcnt(0)" ::: "memory");
    __builtin_amdgcn_s_barrier();

    // ---- pass 1: t[0:64][cb1:cb1+96] = gelu(z @ W1^T + b1) ----
    const int cb1 = wid * 96;
    f32x4 acc1[4][6];
#pragma unroll
    for (int i = 0; i < 4; i++)
#pragma unroll
        for (int j = 0; j < 6; j++) acc1[i][j] = (f32x4){0.f, 0.f, 0.f, 0.f};

#pragma unroll
    for (int kt = 0; kt < 12; kt++) {
        bf16x8 a[4], b[6];
#pragma unroll
        for (int i = 0; i < 4; i++) {
            const int rr = i * 16 + fr;
            const int pos = (kt * 4 + kg) ^ (rr & 7);
            a[i] = *(const bf16x8*)&zS[rr * Df + pos * 8];
        }
#pragma unroll
        for (int j = 0; j < 6; j++)
            b[j] = *(const bf16x8*)(W1T + (size_t)(cb1 + j * 16 + fr) * Df + kt * 32 + kg * 8);
#pragma unroll
        for (int i = 0; i < 4; i++)
#pragma unroll
            for (int j = 0; j < 6; j++)
                acc1[i][j] = __builtin_amdgcn_mfma_f32_16x16x32_bf16(a[i], b[j], acc1[i][j], 0, 0, 0);
    }

    // write t to LDS (swizzled), gelu applied
    float bv1[6];
#pragma unroll
    for (int j = 0; j < 6; j++) bv1[j] = b1[cb1 + j * 16 + fr];
#pragma unroll
    for (int i = 0; i < 4; i++) {
#pragma unroll
        for (int j = 0; j < 6; j++) {
            const int col = cb1 + j * 16 + fr;
#pragma unroll
            for (int r = 0; r < 4; r++) {
                const int row = i * 16 + kg4 + r;
                const int pos = (col >> 3) ^ (row & 7);
                tS[row * Hf + pos * 8 + (col & 7)] = f2bf(gelu_(acc1[i][j][r] + bv1[j]));
            }
        }
    }
    __syncthreads();

    // ---- pass 2: out[0:64][cb2:cb2+48] = x + gelu(t @ W2^T + b2) ----
    const int cb2 = wid * 48;
    f32x4 acc2[4][3];
#pragma unroll
    for (int i = 0; i < 4; i++)
#pragma unroll
        for (int j = 0; j < 3; j++) acc2[i][j] = (f32x4){0.f, 0.f, 0.f, 0.f};

#pragma unroll
    for (int kt = 0; kt < 24; kt++) {
        bf16x8 a[4], b[3];
#pragma unroll
        for (int i = 0; i < 4; i++) {
            const int rr = i * 16 + fr;
            const int pos = (kt * 4 + kg) ^ (rr & 7);
            a[i] = *(const bf16x8*)&tS[rr * Hf + pos * 8];
        }
#pragma unroll
        for (int j = 0; j < 3; j++)
            b[j] = *(const bf16x8*)(W2T + (size_t)(cb2 + j * 16 + fr) * Hf + kt * 32 + kg * 8);
#pragma unroll
        for (int i = 0; i < 4; i++)
#pragma unroll
            for (int j = 0; j < 3; j++)
                acc2[i][j] = __builtin_amdgcn_mfma_f32_16x16x32_bf16(a[i], b[j], acc2[i][j], 0, 0, 0);
    }

    float bv2[3];
#pragma unroll
    for (int j = 0; j < 3; j++) bv2[j] = b2[cb2 + j * 16 + fr];
#pragma unroll
    for (int i = 0; i < 4; i++) {
#pragma unroll
        for (int r = 0; r < 4; r++) {
            const int row = m0 + i * 16 + kg4 + r;
            if (row < M) {
#pragma unroll
                for (int j = 0; j < 3; j++) {
                    const int col = cb2 + j * 16 + fr;
                    size_t o = (size_t)row * Df + col;
                    out[o] = x[o] + gelu_(acc2[i][j][r] + bv2[j]);
                }
            }
        }
    }
}

// ---- Triple-buffered counted-vmcnt GEMM (R8, best measured) for the edge linear ----
// BM=256, BN=128, BK=64. 512 threads = 8 waves (4M x 2N).
// EPI 3: outb[pose[row]] = bf16(acc+bias)
template <int NT, int EPI>
__global__ __launch_bounds__(512, 1) void gemm8(
    const unsigned short* __restrict__ Ab, const unsigned short* __restrict__ Bt,
    const float* __restrict__ bias, int M, int ncols,
    const int* __restrict__ pose,
    unsigned short* __restrict__ outb,
    const float* __restrict__ xres, float* __restrict__ outf, int ldo) {
    constexpr int K = NT * 64;
    __shared__ __align__(16) unsigned short As[3 * 256 * 64];
    __shared__ __align__(16) unsigned short Bs[3 * 128 * 64];

    const int t = threadIdx.x;
    const int nwg = gridDim.x;
    const int orig = blockIdx.x;
    const int xcd = orig & 7;
    const int q = nwg >> 3, r = nwg & 7;
    const int wgid = (xcd < r ? xcd * (q + 1) : r * (q + 1) + (xcd - r) * q) + (orig >> 3);
    const int pp = wgid / ncols;
    const int m0 = pp * 256;
    const int n0 = (wgid - pp * ncols) * 128;

    const int lane = t & 63;
    const int wid = t >> 6;
    const int fr = lane & 15;
    const int kg = lane >> 4;
    const int wm = wid >> 1;
    const int wn = wid & 1;
    const int srow = lane >> 3;
    const int scol = (lane & 7) ^ srow;

    f32x4 acc[4][4];
#pragma unroll
    for (int i = 0; i < 4; i++)
#pragma unroll
        for (int j = 0; j < 4; j++) acc[i][j] = (f32x4){0.f, 0.f, 0.f, 0.f};

#define STG_A(u, kt_, bufi) do {                                                \
        int rr_ = m0 + (u) * 64 + wid * 8 + srow;                               \
        if (rr_ >= M) rr_ = M - 1;                                              \
        gload16(Ab + (size_t)rr_ * K + (kt_) * 64 + (scol << 3),                \
                &As[(bufi) * 16384 + (u) * 4096 + wid * 512]);                  \
    } while (0)
#define STG_B(u, kt_, bufi) do {                                                \
        int rr_ = n0 + (u) * 64 + wid * 8 + srow;                               \
        gload16(Bt + (size_t)rr_ * K + (kt_) * 64 + (scol << 3),                \
                &Bs[(bufi) * 8192 + (u) * 4096 + wid * 512]);                   \
    } while (0)

#pragma unroll
    for (int u = 0; u < 4; u++) STG_A(u, 0, 0);
    STG_B(0, 0, 0); STG_B(1, 0, 0);
#pragma unroll
    for (int u = 0; u < 4; u++) STG_A(u, 1, 1);
    STG_B(0, 1, 1); STG_B(1, 1, 1);
    asm volatile("s_waitcnt vmcnt(6)" ::: "memory");
    __builtin_amdgcn_s_barrier();
    asm volatile("" ::: "memory");

    for (int kt = 0; kt < NT; ++kt) {
        const unsigned short* Ac = As + (kt % 3) * 16384;
        const unsigned short* Bc = Bs + (kt % 3) * 8192;
        const int nb = (kt + 2) % 3;
        const bool st = (kt + 2) < NT;

        if (st) { STG_A(0, kt + 2, nb); STG_A(1, kt + 2, nb); }

        bf16x8 a[4], b[4];
#pragma unroll
        for (int i = 0; i < 4; i++) {
            const int row = wm * 64 + i * 16 + fr;
            a[i] = *(const bf16x8*)&Ac[row * 64 + ((kg ^ (row & 7)) << 3)];
        }
#pragma unroll
        for (int j = 0; j < 4; j++) {
            const int row = wn * 64 + j * 16 + fr;
            b[j] = *(const bf16x8*)&Bc[row * 64 + ((kg ^ (row & 7)) << 3)];
        }
        if (st) { STG_A(2, kt + 2, nb); STG_A(3, kt + 2, nb); }
        __builtin_amdgcn_s_setprio(1);
#pragma unroll
        for (int i = 0; i < 4; i++)
#pragma unroll
            for (int j = 0; j < 4; j++)
                acc[i][j] = __builtin_amdgcn_mfma_f32_16x16x32_bf16(a[i], b[j], acc[i][j], 0, 0, 0);
        __builtin_amdgcn_s_setprio(0);

        if (st) { STG_B(0, kt + 2, nb); STG_B(1, kt + 2, nb); }
#pragma unroll
        for (int i = 0; i < 4; i++) {
            const int row = wm * 64 + i * 16 + fr;
            a[i] = *(const bf16x8*)&Ac[row * 64 + (((4 + kg) ^ (row & 7)) << 3)];
        }
#pragma unroll
        for (int j = 0; j < 4; j++) {
            const int row = wn * 64 + j * 16 + fr;
            b[j] = *(const bf16x8*)&Bc[row * 64 + (((4 + kg) ^ (row & 7)) << 3)];
        }
        __builtin_amdgcn_s_setprio(1);
#pragma unroll
        for (int i = 0; i < 4; i++)
#pragma unroll
            for (int j = 0; j < 4; j++)
                acc[i][j] = __builtin_amdgcn_mfma_f32_16x16x32_bf16(a[i], b[j], acc[i][j], 0, 0, 0);
        __builtin_amdgcn_s_setprio(0);

        if (kt < NT - 1) {
            if (st) asm volatile("s_waitcnt vmcnt(6)" ::: "memory");
            else    asm volatile("s_waitcnt vmcnt(0)" ::: "memory");
            __builtin_amdgcn_s_barrier();
            asm volatile("" ::: "memory");
        }
    }
#undef STG_A
#undef STG_B

    float bi[4];
#pragma unroll
    for (int j = 0; j < 4; j++) bi[j] = bias[n0 + wn * 64 + j * 16 + fr];

    const int kg4 = kg * 4;
#pragma unroll
    for (int i = 0; i < 4; i++) {
        const int rb = m0 + wm * 64 + i * 16 + kg4;
#pragma unroll
        for (int j = 0; j < 4; j++) {
            const int c = n0 + wn * 64 + j * 16 + fr;
#pragma unroll
            for (int r = 0; r < 4; r++) {
                const int row = rb + r;
                if (row < M) {
                    float v = acc[i][j][r] + bi[j];
                    if (EPI == 1) {
                        outb[(size_t)row * ldo + c] = f2bf(gelu_(v));
                    } else if (EPI == 2) {
                        size_t o = (size_t)row * ldo + c;
                        outf[o] = xres[o] + gelu_(v);
                    } else {
                        outb[(size_t)pose[row] * ldo + c] = f2bf(v);
                    }
                }
            }
        }
    }
}

extern "C" void kernel_launch(void* const* d_in, const int* in_sizes, int n_in,
                              void* d_out, int out_size, void* d_ws, size_t ws_size,
                              hipStream_t stream) {
    const float* x = (const float*)d_in[0];
    const float* ea = (const float*)d_in[1];
    const float* gamma = (const float*)d_in[2];
    const float* beta = (const float*)d_in[3];
    const float* epsp = (const float*)d_in[4];
    const float* W_edge = (const float*)d_in[5];
    const float* b_edge = (const float*)d_in[6];
    const float* W1 = (const float*)d_in[7];
    const float* b1 = (const float*)d_in[8];
    const float* W2 = (const float*)d_in[9];
    const float* b2 = (const float*)d_in[10];
    const int* eidx = (const int*)d_in[11];
    float* out = (float*)d_out;
    const int N = in_sizes[0] / Df;
    const int E = in_sizes[1] / Df;
    const int* esrc = eidx;
    const int* edst = eidx + E;

    char* w = (char*)d_ws;
    size_t off_ = 0;
    auto alloc = [&](size_t bytes) { char* p = w + off_; off_ += (bytes + 255) & ~(size_t)255; return p; };
    float* stats = (float*)alloc(2 * Df * sizeof(float));
    float* coef = (float*)alloc(2 * Df * sizeof(float));
    unsigned short* hb = (unsigned short*)alloc((size_t)N * Df * 2);
    unsigned short* zb = (unsigned short*)alloc((size_t)N * Df * 2);
    unsigned short* eab = (unsigned short*)alloc((size_t)E * Df * 2);  // ea as bf16
    unsigned short* WeT = (unsigned short*)alloc((size_t)Df * Df * 2);
    unsigned short* W1T = (unsigned short*)alloc((size_t)Df * Hf * 2);
    unsigned short* W2T = (unsigned short*)alloc((size_t)Hf * Df * 2);
    int* deg = (int*)alloc((size_t)(N + 1) * 4);      // reused as fill cursor
    int* offs = (int*)alloc((size_t)(N + 1) * 4);
    int* srcp = (int*)alloc((size_t)E * 4);
    int* pose = (int*)alloc((size_t)E * 4);
    int* sums = (int*)alloc(64 * 4);
    size_t msgl_bytes = (size_t)E * Df * 2;
    unsigned short* msgl;
    if (off_ + msgl_bytes <= ws_size) msgl = (unsigned short*)alloc(msgl_bytes);
    else msgl = (unsigned short*)d_out;   // dead until mlp_fused writes out
    (void)n_in; (void)out_size;

    hipMemsetAsync(stats, 0, 2 * Df * sizeof(float), stream);
    hipMemsetAsync(deg, 0, (size_t)N * 4, stream);

    // BN + h
    bn_stats<<<1024, 192, 0, stream>>>(x, stats, N);
    bn_finalize<<<1, Df, 0, stream>>>(stats, gamma, beta, coef, N);
    int tot8 = N * Df / 8;
    h_kernel<<<(tot8 + 255) / 256, 256, 0, stream>>>(x, coef, hb, tot8);

    // ea -> bf16
    int etot8 = E * Df / 8;
    cast_bf16<<<(etot8 + 255) / 256, 256, 0, stream>>>(ea, eab, etot8);

    // weights
    wtrans<<<(Df * Df + 255) / 256, 256, 0, stream>>>(W_edge, WeT, Df, Df);
    wtrans<<<(Df * Hf + 255) / 256, 256, 0, stream>>>(W1, W1T, Df, Hf);
    wtrans<<<(Hf * Df + 255) / 256, 256, 0, stream>>>(W2, W2T, Hf, Df);

    // CSR by dst
    int nb = (N + SCAN_CH - 1) / SCAN_CH;
    degree_k<<<(E + 255) / 256, 256, 0, stream>>>(edst, deg, E);
    scan1<<<nb, 256, 0, stream>>>(deg, offs, sums, N);
    scan2<<<1, 1, 0, stream>>>(sums, nb);
    scan3<<<(N + 256) / 256, 256, 0, stream>>>(offs, sums, N, nb);
    hipMemcpyAsync(deg, offs, (size_t)N * 4, hipMemcpyDeviceToDevice, stream);
    fill_k<<<(E + 255) / 256, 256, 0, stream>>>(edst, esrc, deg, srcp, pose, E);

    // edge linear: msgl[pose[e]] = eab[e] @ We^T + b_edge  (bf16, CSR-ordered)
    int ep = (E + 255) / 256;
    gemm8<6, 3><<<dim3(ep * (Df / 128)), 512, 0, stream>>>(
        eab, WeT, b_edge, E, Df / 128, pose, msgl, nullptr, nullptr, Df);

    // gather-reduce -> z (bf16)
    aggregate<<<2048, 256, 0, stream>>>(msgl, hb, offs, srcp, epsp, zb, N);

    // fused MLP: out = x + gelu(gelu(z@W1+b1)@W2+b2)
    mlp_fused<<<(N + 63) / 64, 512, 0, stream>>>(zb, W1T, b1, W2T, b2, x, out, N);
}

// Round 11
// 1146.309 us; speedup vs baseline: 1.1137x; 1.0049x over previous
//
#include <hip/hip_runtime.h>
#include <hip/hip_bf16.h>

#define Df 384
#define Hf 768
#define SCAN_CH 4096

typedef __bf16 bf16x8 __attribute__((ext_vector_type(8)));
typedef float f32x4 __attribute__((ext_vector_type(4)));

struct __attribute__((aligned(4))) U12 { unsigned int x, y, z; };

__device__ inline unsigned short f2bf(float f) {
    __hip_bfloat16 h = __float2bfloat16(f);
    return __builtin_bit_cast(unsigned short, h);
}
__device__ inline float bf2f(unsigned short u) {
    unsigned int v = ((unsigned int)u) << 16;
    return __builtin_bit_cast(float, v);
}
__device__ inline float lobf(unsigned int v) { return bf2f((unsigned short)(v & 0xffff)); }
__device__ inline float hibf(unsigned int v) { return bf2f((unsigned short)(v >> 16)); }
__device__ inline unsigned int pk2(float a, float b) {
    return (unsigned int)f2bf(a) | ((unsigned int)f2bf(b) << 16);
}
__device__ inline float gelu_(float v) {
    return 0.5f * v * (1.0f + erff(v * 0.70710678118654752f));
}
// direct global->LDS, 16B/lane; LDS dest is WAVE-UNIFORM base, HW adds lane*16.
__device__ inline void gload16(const void* g, void* l) {
    __builtin_amdgcn_global_load_lds(
        (const __attribute__((address_space(1))) unsigned int*)g,
        (__attribute__((address_space(3))) unsigned int*)l, 16, 0, 0);
}

// ---- BN column statistics ----
__global__ void bn_stats(const float* __restrict__ x, float* __restrict__ stats, int N) {
    int t = threadIdx.x;                 // 192 threads
    int c4 = (t % 96) * 4;
    int rs = t / 96;
    float s0 = 0, s1 = 0, s2 = 0, s3 = 0, q0 = 0, q1 = 0, q2 = 0, q3 = 0;
    for (int r = blockIdx.x * 2 + rs; r < N; r += gridDim.x * 2) {
        float4 v = *(const float4*)(x + (size_t)r * Df + c4);
        s0 += v.x; s1 += v.y; s2 += v.z; s3 += v.w;
        q0 += v.x * v.x; q1 += v.y * v.y; q2 += v.z * v.z; q3 += v.w * v.w;
    }
    unsafeAtomicAdd(&stats[c4 + 0], s0);
    unsafeAtomicAdd(&stats[c4 + 1], s1);
    unsafeAtomicAdd(&stats[c4 + 2], s2);
    unsafeAtomicAdd(&stats[c4 + 3], s3);
    unsafeAtomicAdd(&stats[Df + c4 + 0], q0);
    unsafeAtomicAdd(&stats[Df + c4 + 1], q1);
    unsafeAtomicAdd(&stats[Df + c4 + 2], q2);
    unsafeAtomicAdd(&stats[Df + c4 + 3], q3);
}

__global__ void bn_finalize(const float* __restrict__ stats,
                            const float* __restrict__ gamma,
                            const float* __restrict__ beta,
                            float* __restrict__ coef, int N) {
    int c = threadIdx.x; // 384
    float invN = 1.0f / (float)N;
    float mu = stats[c] * invN;
    float var = stats[Df + c] * invN - mu * mu;
    float rs = rsqrtf(var + 1e-5f);
    float a = gamma[c] * rs;
    coef[c] = a;
    coef[Df + c] = beta[c] - mu * a;
}

// ---- h = x*a + b  ->  bf16 ----
__global__ void h_kernel(const float* __restrict__ x, const float* __restrict__ coef,
                         unsigned short* __restrict__ hb, int tot8) {
    int i = blockIdx.x * 256 + threadIdx.x;
    if (i >= tot8) return;
    size_t base = (size_t)i * 8;
    int c = (int)(base % Df);
    float4 x0 = *(const float4*)(x + base);
    float4 x1 = *(const float4*)(x + base + 4);
    const float* a = coef + c;
    const float* b = coef + Df + c;
    uint4 o;
    o.x = pk2(x0.x * a[0] + b[0], x0.y * a[1] + b[1]);
    o.y = pk2(x0.z * a[2] + b[2], x0.w * a[3] + b[3]);
    o.z = pk2(x1.x * a[4] + b[4], x1.y * a[5] + b[5]);
    o.w = pk2(x1.z * a[6] + b[6], x1.w * a[7] + b[7]);
    *(uint4*)(hb + base) = o;
}

// ---- all three weight transposes in one dispatch ----
__global__ void wtrans3(const float* __restrict__ We, const float* __restrict__ W1,
                        const float* __restrict__ W2,
                        unsigned short* __restrict__ WeT, unsigned short* __restrict__ W1T,
                        unsigned short* __restrict__ W2T) {
    int idx = blockIdx.x * 256 + threadIdx.x;
    if (idx < Df * Df) {
        int k = idx / Df, n = idx % Df;
        WeT[n * Df + k] = f2bf(We[idx]);
    } else if (idx < Df * Df + Df * Hf) {
        int i = idx - Df * Df;
        int k = i / Hf, n = i % Hf;
        W1T[(size_t)n * Df + k] = f2bf(W1[i]);
    } else if (idx < Df * Df + 2 * Df * Hf) {
        int i = idx - (Df * Df + Df * Hf);
        int k = i / Df, n = i % Df;
        W2T[(size_t)n * Hf + k] = f2bf(W2[i]);
    }
}

// ---- CSR build ----
__global__ void degree_k(const int* __restrict__ dst, int* __restrict__ deg, int E) {
    int e = blockIdx.x * 256 + threadIdx.x;
    if (e < E) atomicAdd(&deg[dst[e]], 1);
}

__global__ void scan1(const int* __restrict__ deg, int* __restrict__ off,
                      int* __restrict__ sums, int N) {
    __shared__ int ts[256];
    int t = threadIdx.x;
    int base = blockIdx.x * SCAN_CH + t * 16;
    int v[16];
    int s = 0;
    for (int j = 0; j < 16; j++) {
        int idx = base + j;
        int d = (idx < N) ? deg[idx] : 0;
        v[j] = s;
        s += d;
    }
    ts[t] = s;
    __syncthreads();
    for (int o = 1; o < 256; o <<= 1) {
        int add = (t >= o) ? ts[t - o] : 0;
        __syncthreads();
        ts[t] += add;
        __syncthreads();
    }
    int pre = t ? ts[t - 1] : 0;
    for (int j = 0; j < 16; j++) {
        int idx = base + j;
        if (idx < N) off[idx] = pre + v[j];
    }
    if (t == 255) sums[blockIdx.x] = ts[255];
}

__global__ void scan2(int* __restrict__ sums, int nb) {
    int acc = 0;
    for (int b = 0; b < nb; b++) { int v = sums[b]; sums[b] = acc; acc += v; }
    sums[nb] = acc;
}

__global__ void scan3(int* __restrict__ off, const int* __restrict__ sums, int N, int nb) {
    int idx = blockIdx.x * 256 + threadIdx.x;
    if (idx < N) off[idx] += sums[idx / SCAN_CH];
    else if (idx == N) off[N] = sums[nb];
}

// fill: pose[e] = CSR slot of edge e; srcp[slot] = src node of that edge
__global__ void fill_k(const int* __restrict__ dst, const int* __restrict__ src,
                       int* __restrict__ cursor, int* __restrict__ srcp,
                       int* __restrict__ pose, int E) {
    int e = blockIdx.x * 256 + threadIdx.x;
    if (e >= E) return;
    int pos = atomicAdd(&cursor[dst[e]], 1);
    srcp[pos] = src[e];
    pose[e] = pos;
}

// ---- gather-reduce: z[i] = (1+eps)*h[i] + sum relu(msgl[p] + h[srcp[p]]) ----
__global__ __launch_bounds__(256) void aggregate(
    const unsigned short* __restrict__ msgl, const unsigned short* __restrict__ hb,
    const int* __restrict__ off, const int* __restrict__ srcp,
    const float* __restrict__ epsp,
    unsigned short* __restrict__ zb, int N) {
    int lane = threadIdx.x & 63;
    int wid = threadIdx.x >> 6;
    int nwaves = gridDim.x * 4;
    float s1p = 1.0f + epsp[0];
    int loff = lane * 6;
    for (int i = blockIdx.x * 4 + wid; i < N; i += nwaves) {
        int o0 = off[i], o1 = off[i + 1];
        float a0 = 0, a1 = 0, a2 = 0, a3 = 0, a4 = 0, a5 = 0;
        for (int p = o0; p < o1; ++p) {
            int s = srcp[p];
            U12 mv = *(const U12*)(msgl + (size_t)p * Df + loff);
            U12 hv = *(const U12*)(hb + (size_t)s * Df + loff);
            a0 += fmaxf(lobf(mv.x) + lobf(hv.x), 0.f);
            a1 += fmaxf(hibf(mv.x) + hibf(hv.x), 0.f);
            a2 += fmaxf(lobf(mv.y) + lobf(hv.y), 0.f);
            a3 += fmaxf(hibf(mv.y) + hibf(hv.y), 0.f);
            a4 += fmaxf(lobf(mv.z) + lobf(hv.z), 0.f);
            a5 += fmaxf(hibf(mv.z) + hibf(hv.z), 0.f);
        }
        U12 hv = *(const U12*)(hb + (size_t)i * Df + loff);
        U12 o;
        o.x = pk2(s1p * lobf(hv.x) + a0, s1p * hibf(hv.x) + a1);
        o.y = pk2(s1p * lobf(hv.y) + a2, s1p * hibf(hv.y) + a3);
        o.z = pk2(s1p * lobf(hv.z) + a4, s1p * hibf(hv.z) + a5);
        *(U12*)(zb + (size_t)i * Df + loff) = o;
    }
}

// ---- Tall-skinny persistent GEMM (GEMM1): tb = bf16(gelu(zb @ W1T^T + b1)) ----
// B-slice (64 cols x 384 k = 48KB) staged to LDS ONCE per block; after the
// single prologue barrier the K/strip loop has ZERO barriers -- 4 waves
// free-run over 128-row strips, A-fragments loaded global->registers.
// 768 blocks = 8 XCD x 8 row-subsets x 12 col-slices; rows are partitioned
// by XCD so the 12 col-slices of a row-panel share that XCD's L2.
// LDS swizzle: unit ^= (col&7) on BOTH stage-source and read (involution,
// 2 lanes/bank = free). 3 blocks/CU (48KB LDS, launch_bounds(256,3)) = 12 waves/CU.
__global__ __launch_bounds__(256, 3) void gemm_ts(
    const unsigned short* __restrict__ Ab,   // M x 384 bf16
    const unsigned short* __restrict__ Bt,   // 768 x 384 bf16 (W1T)
    const float* __restrict__ bias,          // 768
    unsigned short* __restrict__ outb,       // M x 768 bf16
    int M) {
    __shared__ __align__(16) unsigned short Bs[64 * Df];   // 48 KB

    const int t = threadIdx.x;
    const int lane = t & 63;
    const int wid = t >> 6;          // 0..3
    const int fr = lane & 15;
    const int kg = lane >> 4;
    const int orig = blockIdx.x;
    const int xcd = orig & 7;
    const int local = orig >> 3;     // 0..95
    const int cs = local % 12;       // col-slice
    const int rsub = local / 12;     // 0..7
    const int cb = cs * 64;
    const int first = xcd * 8 + rsub;    // 0..63
    const int STRIPS = (M + 127) >> 7;

    // ---- stage B slice once: 3072 16B units, pre-swizzled source ----
#pragma unroll
    for (int s = 0; s < 12; s++) {
        int u = s * 256 + t;
        int col = u / 48;
        int pos = u - col * 48;
        gload16(Bt + (size_t)(cb + col) * Df + ((pos ^ (col & 7)) << 3),
                &Bs[(s * 256 + wid * 64) * 8]);
    }
    asm volatile("s_waitcnt vmcnt(0)" ::: "memory");
    __builtin_amdgcn_s_barrier();

    float bv[4];
#pragma unroll
    for (int j = 0; j < 4; j++) bv[j] = bias[cb + j * 16 + fr];

    for (int s = first; s < STRIPS; s += 64) {
        const int r0 = s * 128 + wid * 32;
        int ra0 = r0 + fr;       if (ra0 >= M) ra0 = M - 1;
        int ra1 = r0 + 16 + fr;  if (ra1 >= M) ra1 = M - 1;
        const unsigned short* pA0 = Ab + (size_t)ra0 * Df + kg * 8;
        const unsigned short* pA1 = Ab + (size_t)ra1 * Df + kg * 8;

        f32x4 acc[2][4];
#pragma unroll
        for (int i = 0; i < 2; i++)
#pragma unroll
            for (int j = 0; j < 4; j++) acc[i][j] = (f32x4){0.f, 0.f, 0.f, 0.f};

        uint4 a0 = *(const uint4*)(pA0);
        uint4 a1 = *(const uint4*)(pA1);
#pragma unroll
        for (int kt = 0; kt < 12; kt++) {
            uint4 n0, n1;
            if (kt < 11) {
                n0 = *(const uint4*)(pA0 + (kt + 1) * 32);
                n1 = *(const uint4*)(pA1 + (kt + 1) * 32);
            } else { n0 = a0; n1 = a1; }
            bf16x8 bf[4];
#pragma unroll
            for (int j = 0; j < 4; j++) {
                const int cl = j * 16 + fr;
                const int unit = (kt * 4 + kg) ^ (cl & 7);
                bf[j] = *(const bf16x8*)&Bs[(cl * 48 + unit) * 8];
            }
            bf16x8 av0 = __builtin_bit_cast(bf16x8, a0);
            bf16x8 av1 = __builtin_bit_cast(bf16x8, a1);
#pragma unroll
            for (int j = 0; j < 4; j++) {
                acc[0][j] = __builtin_amdgcn_mfma_f32_16x16x32_bf16(av0, bf[j], acc[0][j], 0, 0, 0);
                acc[1][j] = __builtin_amdgcn_mfma_f32_16x16x32_bf16(av1, bf[j], acc[1][j], 0, 0, 0);
            }
            a0 = n0; a1 = n1;
        }

        const int kg4 = kg * 4;
#pragma unroll
        for (int i = 0; i < 2; i++) {
            const int rb = r0 + i * 16 + kg4;
#pragma unroll
            for (int r = 0; r < 4; r++) {
                const int row = rb + r;
                if (row < M) {
#pragma unroll
                    for (int j = 0; j < 4; j++) {
                        outb[(size_t)row * Hf + cb + j * 16 + fr] =
                            f2bf(gelu_(acc[i][j][r] + bv[j]));
                    }
                }
            }
        }
    }
}

// ---- R4 2-phase dbuf GEMM (273us measured): C = A @ Bt^T (+bias + epilogue) ----
// EPI 2: out = xres + gelu(acc + bias) (f32); EPI 3: outb[pose[row]] = bf16(acc+bias)
template <int EPI, bool ABF16>
__global__ __launch_bounds__(256) void gemm_fused(
    const void* __restrict__ Ap, const unsigned short* __restrict__ Bt,
    const float* __restrict__ bias, int M, int K, int ncols,
    const int* __restrict__ pose,
    unsigned short* __restrict__ outb,
    const float* __restrict__ xres, float* __restrict__ outf, int ldo) {
    __shared__ __align__(16) unsigned short As[2][128 * 32];
    __shared__ __align__(16) unsigned short Bs[2][128 * 32];
    const int t = threadIdx.x;
    const int nwg = gridDim.x;
    const int orig = blockIdx.x;
    const int xcd = orig & 7;
    const int q = nwg >> 3, r = nwg & 7;
    const int wgid = (xcd < r ? xcd * (q + 1) : r * (q + 1) + (xcd - r) * q) + (orig >> 3);
    const int pp = wgid / ncols;
    const int m0 = pp * 128;
    const int n0 = (wgid - pp * ncols) * 128;

    const int lane = t & 63;
    const int wid = t >> 6;
    const int wr = (wid >> 1) << 6;
    const int wc = (wid & 1) << 6;
    const int fr = lane & 15;
    const int kg = lane >> 4;
    const int crow = lane >> 2;
    const int cseg = lane & 3;
    const int sr = t >> 1;
    const int sh = (t & 1) << 4;

    f32x4 acc[4][4];
#pragma unroll
    for (int i = 0; i < 4; i++)
#pragma unroll
        for (int j = 0; j < 4; j++) acc[i][j] = (f32x4){0.f, 0.f, 0.f, 0.f};

    const bool arok = (m0 + sr) < M;
    const size_t arowoff = (size_t)(m0 + sr) * K;
    const int NT = K >> 5;

    auto stageB = [&](int buf, int k0) {
#pragma unroll
        for (int h = 0; h < 2; h++) {
            const int rbase = wid * 32 + h * 16;
            gload16(Bt + (size_t)(n0 + rbase + crow) * K + k0 + cseg * 8,
                    &Bs[buf][rbase * 32]);
        }
    };
    auto stageA16 = [&](int buf, int k0) {
        const unsigned short* Ab = (const unsigned short*)Ap;
#pragma unroll
        for (int h = 0; h < 2; h++) {
            const int rbase = wid * 32 + h * 16;
            if (m0 + rbase + crow < M)
                gload16(Ab + (size_t)(m0 + rbase + crow) * K + k0 + cseg * 8,
                        &As[buf][rbase * 32]);
        }
    };

    if (ABF16) {
        stageA16(0, 0);
    } else if (arok) {
        const float4* p = (const float4*)((const float*)Ap + arowoff + sh);
        float4 f0 = p[0], f1 = p[1], f2 = p[2], f3 = p[3];
        uint4 w0, w1;
        w0.x = pk2(f0.x, f0.y); w0.y = pk2(f0.z, f0.w);
        w0.z = pk2(f1.x, f1.y); w0.w = pk2(f1.z, f1.w);
        w1.x = pk2(f2.x, f2.y); w1.y = pk2(f2.z, f2.w);
        w1.z = pk2(f3.x, f3.y); w1.w = pk2(f3.z, f3.w);
        *(uint4*)&As[0][sr * 32 + sh] = w0;
        *(uint4*)&As[0][sr * 32 + sh + 8] = w1;
    }
    stageB(0, 0);
    __syncthreads();

    int cur = 0;
    for (int kt = 0; kt < NT; ++kt) {
        const int nxt = cur ^ 1;
        const bool more = (kt + 1) < NT;
        float4 f0, f1, f2, f3;
        if (more) {
            const int k0n = (kt + 1) * 32;
            if (ABF16) {
                stageA16(nxt, k0n);
            } else if (arok) {
                const float4* p = (const float4*)((const float*)Ap + arowoff + k0n + sh);
                f0 = p[0]; f1 = p[1]; f2 = p[2]; f3 = p[3];
            }
            stageB(nxt, k0n);
        }

        bf16x8 a[4], b[4];
#pragma unroll
        for (int i = 0; i < 4; i++) a[i] = *(const bf16x8*)&As[cur][(wr + i * 16 + fr) * 32 + kg * 8];
#pragma unroll
        for (int j = 0; j < 4; j++) b[j] = *(const bf16x8*)&Bs[cur][(wc + j * 16 + fr) * 32 + kg * 8];
#pragma unroll
        for (int i = 0; i < 4; i++)
#pragma unroll
            for (int j = 0; j < 4; j++)
                acc[i][j] = __builtin_amdgcn_mfma_f32_16x16x32_bf16(a[i], b[j], acc[i][j], 0, 0, 0);

        if (!ABF16 && more && arok) {
            uint4 w0, w1;
            w0.x = pk2(f0.x, f0.y); w0.y = pk2(f0.z, f0.w);
            w0.z = pk2(f1.x, f1.y); w0.w = pk2(f1.z, f1.w);
            w1.x = pk2(f2.x, f2.y); w1.y = pk2(f2.z, f2.w);
            w1.z = pk2(f3.x, f3.y); w1.w = pk2(f3.z, f3.w);
            *(uint4*)&As[nxt][sr * 32 + sh] = w0;
            *(uint4*)&As[nxt][sr * 32 + sh + 8] = w1;
        }
        __syncthreads();
        cur = nxt;
    }

    const int kg4 = kg * 4;
#pragma unroll
    for (int i = 0; i < 4; i++) {
        const int rb = m0 + wr + i * 16 + kg4;
#pragma unroll
        for (int j = 0; j < 4; j++) {
            const int c = n0 + wc + j * 16 + fr;
#pragma unroll
            for (int r = 0; r < 4; r++) {
                const int row = rb + r;
                if (row < M) {
                    float v = acc[i][j][r] + bias[c];
                    if (EPI == 2) {
                        size_t o = (size_t)row * ldo + c;
                        outf[o] = xres[o] + gelu_(v);
                    } else {
                        outb[(size_t)pose[row] * ldo + c] = f2bf(v);
                    }
                }
            }
        }
    }
}

extern "C" void kernel_launch(void* const* d_in, const int* in_sizes, int n_in,
                              void* d_out, int out_size, void* d_ws, size_t ws_size,
                              hipStream_t stream) {
    const float* x = (const float*)d_in[0];
    const float* ea = (const float*)d_in[1];
    const float* gamma = (const float*)d_in[2];
    const float* beta = (const float*)d_in[3];
    const float* epsp = (const float*)d_in[4];
    const float* W_edge = (const float*)d_in[5];
    const float* b_edge = (const float*)d_in[6];
    const float* W1 = (const float*)d_in[7];
    const float* b1 = (const float*)d_in[8];
    const float* W2 = (const float*)d_in[9];
    const float* b2 = (const float*)d_in[10];
    const int* eidx = (const int*)d_in[11];
    float* out = (float*)d_out;
    const int N = in_sizes[0] / Df;
    const int E = in_sizes[1] / Df;
    const int* esrc = eidx;
    const int* edst = eidx + E;

    char* w = (char*)d_ws;
    size_t off_ = 0;
    auto alloc = [&](size_t bytes) { char* p = w + off_; off_ += (bytes + 255) & ~(size_t)255; return p; };
    float* stats = (float*)alloc(2 * Df * sizeof(float));
    float* coef = (float*)alloc(2 * Df * sizeof(float));
    unsigned short* hb = (unsigned short*)alloc((size_t)N * Df * 2);
    unsigned short* zb = (unsigned short*)alloc((size_t)N * Df * 2);
    unsigned short* tb = (unsigned short*)alloc((size_t)N * Hf * 2);
    unsigned short* WeT = (unsigned short*)alloc((size_t)Df * Df * 2);
    unsigned short* W1T = (unsigned short*)alloc((size_t)Df * Hf * 2);
    unsigned short* W2T = (unsigned short*)alloc((size_t)Hf * Df * 2);
    int* deg = (int*)alloc((size_t)(N + 1) * 4);      // reused as fill cursor
    int* offs = (int*)alloc((size_t)(N + 1) * 4);
    int* srcp = (int*)alloc((size_t)E * 4);
    int* pose = (int*)alloc((size_t)E * 4);
    int* sums = (int*)alloc(64 * 4);
    size_t msgl_bytes = (size_t)E * Df * 2;
    unsigned short* msgl;
    if (off_ + msgl_bytes <= ws_size) msgl = (unsigned short*)alloc(msgl_bytes);
    else msgl = (unsigned short*)d_out;   // dead until final GEMM writes it
    (void)n_in; (void)out_size;

    hipMemsetAsync(stats, 0, 2 * Df * sizeof(float), stream);
    hipMemsetAsync(deg, 0, (size_t)N * 4, stream);

    // BN + h
    bn_stats<<<1024, 192, 0, stream>>>(x, stats, N);
    bn_finalize<<<1, Df, 0, stream>>>(stats, gamma, beta, coef, N);
    int tot8 = N * Df / 8;
    h_kernel<<<(tot8 + 255) / 256, 256, 0, stream>>>(x, coef, hb, tot8);

    // weights (one dispatch)
    wtrans3<<<(Df * Df + 2 * Df * Hf + 255) / 256, 256, 0, stream>>>(
        W_edge, W1, W2, WeT, W1T, W2T);

    // CSR by dst
    int nb = (N + SCAN_CH - 1) / SCAN_CH;
    degree_k<<<(E + 255) / 256, 256, 0, stream>>>(edst, deg, E);
    scan1<<<nb, 256, 0, stream>>>(deg, offs, sums, N);
    scan2<<<1, 1, 0, stream>>>(sums, nb);
    scan3<<<(N + 256) / 256, 256, 0, stream>>>(offs, sums, N, nb);
    hipMemcpyAsync(deg, offs, (size_t)N * 4, hipMemcpyDeviceToDevice, stream);
    fill_k<<<(E + 255) / 256, 256, 0, stream>>>(edst, esrc, deg, srcp, pose, E);

    // edge linear: msgl[pose[e]] = ea[e] @ We^T + b_edge  (f32 A path, bf16 out)
    int ep = (E + 127) / 128;
    gemm_fused<3, false><<<dim3(ep * (Df / 128)), 256, 0, stream>>>(
        ea, WeT, b_edge, E, Df, Df / 128, pose, msgl, nullptr, nullptr, Df);

    // gather-reduce -> z (bf16)
    aggregate<<<2048, 256, 0, stream>>>(msgl, hb, offs, srcp, epsp, zb, N);

    // GEMM1 (tall-skinny persistent): tb = bf16(gelu(zb @ W1T^T + b1))
    gemm_ts<<<768, 256, 0, stream>>>(zb, W1T, b1, tb, N);

    // GEMM2: out = x + gelu(tb @ W2T^T + b2)
    int np = (N + 127) / 128;
    gemm_fused<2, true><<<dim3(np * (Df / 128)), 256, 0, stream>>>(
        tb, W2T, b2, N, Hf, Df / 128, nullptr, nullptr, x, out, Df);
}

// Round 12
// 1029.855 us; speedup vs baseline: 1.2397x; 1.1131x over previous
//
#include <hip/hip_runtime.h>
#include <hip/hip_bf16.h>

#define Df 384
#define Hf 768
#define SCAN_CH 4096

typedef __bf16 bf16x8 __attribute__((ext_vector_type(8)));
typedef float f32x4 __attribute__((ext_vector_type(4)));

struct __attribute__((aligned(4))) U12 { unsigned int x, y, z; };

__device__ inline unsigned short f2bf(float f) {
    __hip_bfloat16 h = __float2bfloat16(f);
    return __builtin_bit_cast(unsigned short, h);
}
__device__ inline float bf2f(unsigned short u) {
    unsigned int v = ((unsigned int)u) << 16;
    return __builtin_bit_cast(float, v);
}
__device__ inline float lobf(unsigned int v) { return bf2f((unsigned short)(v & 0xffff)); }
__device__ inline float hibf(unsigned int v) { return bf2f((unsigned short)(v >> 16)); }
__device__ inline unsigned int pk2(float a, float b) {
    return (unsigned int)f2bf(a) | ((unsigned int)f2bf(b) << 16);
}
__device__ inline float gelu_(float v) {
    return 0.5f * v * (1.0f + erff(v * 0.70710678118654752f));
}
// direct global->LDS, 16B/lane; LDS dest is WAVE-UNIFORM base, HW adds lane*16.
__device__ inline void gload16(const void* g, void* l) {
    __builtin_amdgcn_global_load_lds(
        (const __attribute__((address_space(1))) unsigned int*)g,
        (__attribute__((address_space(3))) unsigned int*)l, 16, 0, 0);
}

// ---- BN column statistics ----
__global__ void bn_stats(const float* __restrict__ x, float* __restrict__ stats, int N) {
    int t = threadIdx.x;                 // 192 threads
    int c4 = (t % 96) * 4;
    int rs = t / 96;
    float s0 = 0, s1 = 0, s2 = 0, s3 = 0, q0 = 0, q1 = 0, q2 = 0, q3 = 0;
    for (int r = blockIdx.x * 2 + rs; r < N; r += gridDim.x * 2) {
        float4 v = *(const float4*)(x + (size_t)r * Df + c4);
        s0 += v.x; s1 += v.y; s2 += v.z; s3 += v.w;
        q0 += v.x * v.x; q1 += v.y * v.y; q2 += v.z * v.z; q3 += v.w * v.w;
    }
    unsafeAtomicAdd(&stats[c4 + 0], s0);
    unsafeAtomicAdd(&stats[c4 + 1], s1);
    unsafeAtomicAdd(&stats[c4 + 2], s2);
    unsafeAtomicAdd(&stats[c4 + 3], s3);
    unsafeAtomicAdd(&stats[Df + c4 + 0], q0);
    unsafeAtomicAdd(&stats[Df + c4 + 1], q1);
    unsafeAtomicAdd(&stats[Df + c4 + 2], q2);
    unsafeAtomicAdd(&stats[Df + c4 + 3], q3);
}

__global__ void bn_finalize(const float* __restrict__ stats,
                            const float* __restrict__ gamma,
                            const float* __restrict__ beta,
                            float* __restrict__ coef, int N) {
    int c = threadIdx.x; // 384
    float invN = 1.0f / (float)N;
    float mu = stats[c] * invN;
    float var = stats[Df + c] * invN - mu * mu;
    float rs = rsqrtf(var + 1e-5f);
    float a = gamma[c] * rs;
    coef[c] = a;
    coef[Df + c] = beta[c] - mu * a;
}

// ---- h = x*a + b  ->  bf16 ----
__global__ void h_kernel(const float* __restrict__ x, const float* __restrict__ coef,
                         unsigned short* __restrict__ hb, int tot8) {
    int i = blockIdx.x * 256 + threadIdx.x;
    if (i >= tot8) return;
    size_t base = (size_t)i * 8;
    int c = (int)(base % Df);
    float4 x0 = *(const float4*)(x + base);
    float4 x1 = *(const float4*)(x + base + 4);
    const float* a = coef + c;
    const float* b = coef + Df + c;
    uint4 o;
    o.x = pk2(x0.x * a[0] + b[0], x0.y * a[1] + b[1]);
    o.y = pk2(x0.z * a[2] + b[2], x0.w * a[3] + b[3]);
    o.z = pk2(x1.x * a[4] + b[4], x1.y * a[5] + b[5]);
    o.w = pk2(x1.z * a[6] + b[6], x1.w * a[7] + b[7]);
    *(uint4*)(hb + base) = o;
}

// ---- all three weight transposes in one dispatch ----
__global__ void wtrans3(const float* __restrict__ We, const float* __restrict__ W1,
                        const float* __restrict__ W2,
                        unsigned short* __restrict__ WeT, unsigned short* __restrict__ W1T,
                        unsigned short* __restrict__ W2T) {
    int idx = blockIdx.x * 256 + threadIdx.x;
    if (idx < Df * Df) {
        int k = idx / Df, n = idx % Df;
        WeT[n * Df + k] = f2bf(We[idx]);
    } else if (idx < Df * Df + Df * Hf) {
        int i = idx - Df * Df;
        int k = i / Hf, n = i % Hf;
        W1T[(size_t)n * Df + k] = f2bf(W1[i]);
    } else if (idx < Df * Df + 2 * Df * Hf) {
        int i = idx - (Df * Df + Df * Hf);
        int k = i / Df, n = i % Df;
        W2T[(size_t)n * Hf + k] = f2bf(W2[i]);
    }
}

// ---- CSR build ----
__global__ void degree_k(const int* __restrict__ dst, int* __restrict__ deg, int E) {
    int e = blockIdx.x * 256 + threadIdx.x;
    if (e < E) atomicAdd(&deg[dst[e]], 1);
}

__global__ void scan1(const int* __restrict__ deg, int* __restrict__ off,
                      int* __restrict__ sums, int N) {
    __shared__ int ts[256];
    int t = threadIdx.x;
    int base = blockIdx.x * SCAN_CH + t * 16;
    int v[16];
    int s = 0;
    for (int j = 0; j < 16; j++) {
        int idx = base + j;
        int d = (idx < N) ? deg[idx] : 0;
        v[j] = s;
        s += d;
    }
    ts[t] = s;
    __syncthreads();
    for (int o = 1; o < 256; o <<= 1) {
        int add = (t >= o) ? ts[t - o] : 0;
        __syncthreads();
        ts[t] += add;
        __syncthreads();
    }
    int pre = t ? ts[t - 1] : 0;
    for (int j = 0; j < 16; j++) {
        int idx = base + j;
        if (idx < N) off[idx] = pre + v[j];
    }
    if (t == 255) sums[blockIdx.x] = ts[255];
}

__global__ void scan2(int* __restrict__ sums, int nb) {
    int acc = 0;
    for (int b = 0; b < nb; b++) { int v = sums[b]; sums[b] = acc; acc += v; }
    sums[nb] = acc;
}

__global__ void scan3(int* __restrict__ off, const int* __restrict__ sums, int N, int nb) {
    int idx = blockIdx.x * 256 + threadIdx.x;
    if (idx < N) off[idx] += sums[idx / SCAN_CH];
    else if (idx == N) off[N] = sums[nb];
}

// fill: pose[e] = CSR slot of edge e; srcp[slot] = src node of that edge
__global__ void fill_k(const int* __restrict__ dst, const int* __restrict__ src,
                       int* __restrict__ cursor, int* __restrict__ srcp,
                       int* __restrict__ pose, int E) {
    int e = blockIdx.x * 256 + threadIdx.x;
    if (e >= E) return;
    int pos = atomicAdd(&cursor[dst[e]], 1);
    srcp[pos] = src[e];
    pose[e] = pos;
}

// ---- gather-reduce: z[i] = (1+eps)*h[i] + sum relu(msgl[p] + h[srcp[p]]) ----
__global__ __launch_bounds__(256) void aggregate(
    const unsigned short* __restrict__ msgl, const unsigned short* __restrict__ hb,
    const int* __restrict__ off, const int* __restrict__ srcp,
    const float* __restrict__ epsp,
    unsigned short* __restrict__ zb, int N) {
    int lane = threadIdx.x & 63;
    int wid = threadIdx.x >> 6;
    int nwaves = gridDim.x * 4;
    float s1p = 1.0f + epsp[0];
    int loff = lane * 6;
    for (int i = blockIdx.x * 4 + wid; i < N; i += nwaves) {
        int o0 = off[i], o1 = off[i + 1];
        float a0 = 0, a1 = 0, a2 = 0, a3 = 0, a4 = 0, a5 = 0;
        for (int p = o0; p < o1; ++p) {
            int s = srcp[p];
            U12 mv = *(const U12*)(msgl + (size_t)p * Df + loff);
            U12 hv = *(const U12*)(hb + (size_t)s * Df + loff);
            a0 += fmaxf(lobf(mv.x) + lobf(hv.x), 0.f);
            a1 += fmaxf(hibf(mv.x) + hibf(hv.x), 0.f);
            a2 += fmaxf(lobf(mv.y) + lobf(hv.y), 0.f);
            a3 += fmaxf(hibf(mv.y) + hibf(hv.y), 0.f);
            a4 += fmaxf(lobf(mv.z) + lobf(hv.z), 0.f);
            a5 += fmaxf(hibf(mv.z) + hibf(hv.z), 0.f);
        }
        U12 hv = *(const U12*)(hb + (size_t)i * Df + loff);
        U12 o;
        o.x = pk2(s1p * lobf(hv.x) + a0, s1p * hibf(hv.x) + a1);
        o.y = pk2(s1p * lobf(hv.y) + a2, s1p * hibf(hv.y) + a3);
        o.z = pk2(s1p * lobf(hv.z) + a4, s1p * hibf(hv.z) + a5);
        *(U12*)(zb + (size_t)i * Df + loff) = o;
    }
}

// ---- Strip GEMM: one block = one 128-row strip x one 64-col slice ----
// Grid col-fastest + m204 XCD chunking -> same-strip slices co-resident on one
// XCD's L2 (R4-proven ~2x dedup). B-slice staged once per 384-k half (48KB,
// 3 blocks/CU = 12 waves/CU); K-loop BARRIER-FREE; A streams global->regs
// with next-tile prefetch (R11's 2.37 TB/s loop). EPI 1 (bf16 out): C staged
// through dead B-LDS -> 16B/lane full-line stores. EPI 2 (f32 out + x residual):
// direct 64B-coalesced stores.
template <int KTOT, int EPI>
__global__ __launch_bounds__(256, 3) void gemm_strip(
    const unsigned short* __restrict__ Ab, const unsigned short* __restrict__ Bt,
    const float* __restrict__ bias,
    unsigned short* __restrict__ outb, const float* __restrict__ xres,
    float* __restrict__ outf, int M, int ncols, int ldo) {
    constexpr int NKT = KTOT / 32;    // total k-tiles
    constexpr int NH = KTOT / 384;    // 48KB B halves (1 or 2)
    __shared__ __align__(16) unsigned short Bs[64 * 48 * 8];   // 48 KB

    const int t = threadIdx.x;
    const int nwg = gridDim.x;
    const int orig = blockIdx.x;
    const int xcd = orig & 7;
    const int q = nwg >> 3, r = nwg & 7;
    const int wgid = (xcd < r ? xcd * (q + 1) : r * (q + 1) + (xcd - r) * q) + (orig >> 3);
    const int strip = wgid / ncols;
    const int cb = (wgid - strip * ncols) * 64;

    const int lane = t & 63;
    const int wid = t >> 6;
    const int fr = lane & 15;
    const int kg = lane >> 4;

    auto stageB = [&](int koff) {
#pragma unroll
        for (int s_ = 0; s_ < 12; s_++) {
            int u = s_ * 256 + t;
            int col = u / 48;
            int pos = u - col * 48;
            gload16(Bt + (size_t)(cb + col) * KTOT + koff + ((pos ^ (col & 7)) << 3),
                    &Bs[(s_ * 256 + wid * 64) * 8]);
        }
    };

    int ra0 = strip * 128 + wid * 32 + fr;      if (ra0 >= M) ra0 = M - 1;
    int ra1 = strip * 128 + wid * 32 + 16 + fr; if (ra1 >= M) ra1 = M - 1;
    const unsigned short* pA0 = Ab + (size_t)ra0 * KTOT + kg * 8;
    const unsigned short* pA1 = Ab + (size_t)ra1 * KTOT + kg * 8;

    f32x4 acc[2][4];
#pragma unroll
    for (int i = 0; i < 2; i++)
#pragma unroll
        for (int j = 0; j < 4; j++) acc[i][j] = (f32x4){0.f, 0.f, 0.f, 0.f};

    stageB(0);
    uint4 a0 = *(const uint4*)(pA0);
    uint4 a1 = *(const uint4*)(pA1);
    asm volatile("s_waitcnt vmcnt(0)" ::: "memory");
    __builtin_amdgcn_s_barrier();

#pragma unroll
    for (int h = 0; h < NH; h++) {
        if (h > 0) {
            __syncthreads();          // all waves done with previous B half
            stageB(h * 384);
            asm volatile("s_waitcnt vmcnt(0)" ::: "memory");
            __builtin_amdgcn_s_barrier();
        }
#pragma unroll
        for (int ktl = 0; ktl < 12; ktl++) {
            const int kt = h * 12 + ktl;
            uint4 n0, n1;
            if (kt < NKT - 1) {
                n0 = *(const uint4*)(pA0 + (kt + 1) * 32);
                n1 = *(const uint4*)(pA1 + (kt + 1) * 32);
            } else { n0 = a0; n1 = a1; }
            bf16x8 bf[4];
#pragma unroll
            for (int j = 0; j < 4; j++) {
                const int cl = j * 16 + fr;
                const int unit = (ktl * 4 + kg) ^ (cl & 7);
                bf[j] = *(const bf16x8*)&Bs[(cl * 48 + unit) * 8];
            }
            bf16x8 av0 = __builtin_bit_cast(bf16x8, a0);
            bf16x8 av1 = __builtin_bit_cast(bf16x8, a1);
#pragma unroll
            for (int j = 0; j < 4; j++) {
                acc[0][j] = __builtin_amdgcn_mfma_f32_16x16x32_bf16(av0, bf[j], acc[0][j], 0, 0, 0);
                acc[1][j] = __builtin_amdgcn_mfma_f32_16x16x32_bf16(av1, bf[j], acc[1][j], 0, 0, 0);
            }
            a0 = n0; a1 = n1;
        }
    }

    float bv[4];
#pragma unroll
    for (int j = 0; j < 4; j++) bv[j] = bias[cb + j * 16 + fr];
    const int kg4 = kg * 4;
    const int rbase = strip * 128;

    if (EPI == 1) {
        // stage C through dead B-LDS (stride 72 shorts: 16B-aligned rows)
        __syncthreads();
        unsigned short* Ct = Bs;
#pragma unroll
        for (int i = 0; i < 2; i++) {
            const int rl = wid * 32 + i * 16 + kg4;
#pragma unroll
            for (int j = 0; j < 4; j++) {
#pragma unroll
                for (int rr = 0; rr < 4; rr++)
                    Ct[(rl + rr) * 72 + j * 16 + fr] = f2bf(gelu_(acc[i][j][rr] + bv[j]));
            }
        }
        __syncthreads();
#pragma unroll
        for (int s_ = 0; s_ < 4; s_++) {
            int u = s_ * 256 + t;
            int rl = u >> 3, seg = u & 7;
            int grow = rbase + rl;
            if (grow < M)
                *(uint4*)(outb + (size_t)grow * ldo + cb + seg * 8) =
                    *(const uint4*)&Ct[rl * 72 + seg * 8];
        }
    } else {
#pragma unroll
        for (int i = 0; i < 2; i++) {
            const int rb = rbase + wid * 32 + i * 16 + kg4;
#pragma unroll
            for (int rr = 0; rr < 4; rr++) {
                const int row = rb + rr;
                if (row < M) {
#pragma unroll
                    for (int j = 0; j < 4; j++) {
                        size_t o = (size_t)row * ldo + cb + j * 16 + fr;
                        outf[o] = xres[o] + gelu_(acc[i][j][rr] + bv[j]);
                    }
                }
            }
        }
    }
}

// ---- R4 2-phase dbuf GEMM (273us measured) for the edge linear ----
// EPI 3: outb[pose[row]] = bf16(acc+bias)
template <int EPI, bool ABF16>
__global__ __launch_bounds__(256) void gemm_fused(
    const void* __restrict__ Ap, const unsigned short* __restrict__ Bt,
    const float* __restrict__ bias, int M, int K, int ncols,
    const int* __restrict__ pose,
    unsigned short* __restrict__ outb,
    const float* __restrict__ xres, float* __restrict__ outf, int ldo) {
    __shared__ __align__(16) unsigned short As[2][128 * 32];
    __shared__ __align__(16) unsigned short Bs[2][128 * 32];
    const int t = threadIdx.x;
    const int nwg = gridDim.x;
    const int orig = blockIdx.x;
    const int xcd = orig & 7;
    const int q = nwg >> 3, r = nwg & 7;
    const int wgid = (xcd < r ? xcd * (q + 1) : r * (q + 1) + (xcd - r) * q) + (orig >> 3);
    const int pp = wgid / ncols;
    const int m0 = pp * 128;
    const int n0 = (wgid - pp * ncols) * 128;

    const int lane = t & 63;
    const int wid = t >> 6;
    const int wr = (wid >> 1) << 6;
    const int wc = (wid & 1) << 6;
    const int fr = lane & 15;
    const int kg = lane >> 4;
    const int crow = lane >> 2;
    const int cseg = lane & 3;
    const int sr = t >> 1;
    const int sh = (t & 1) << 4;

    f32x4 acc[4][4];
#pragma unroll
    for (int i = 0; i < 4; i++)
#pragma unroll
        for (int j = 0; j < 4; j++) acc[i][j] = (f32x4){0.f, 0.f, 0.f, 0.f};

    const bool arok = (m0 + sr) < M;
    const size_t arowoff = (size_t)(m0 + sr) * K;
    const int NT = K >> 5;

    auto stageB = [&](int buf, int k0) {
#pragma unroll
        for (int h = 0; h < 2; h++) {
            const int rbase = wid * 32 + h * 16;
            gload16(Bt + (size_t)(n0 + rbase + crow) * K + k0 + cseg * 8,
                    &Bs[buf][rbase * 32]);
        }
    };
    auto stageA16 = [&](int buf, int k0) {
        const unsigned short* Ab = (const unsigned short*)Ap;
#pragma unroll
        for (int h = 0; h < 2; h++) {
            const int rbase = wid * 32 + h * 16;
            if (m0 + rbase + crow < M)
                gload16(Ab + (size_t)(m0 + rbase + crow) * K + k0 + cseg * 8,
                        &As[buf][rbase * 32]);
        }
    };

    if (ABF16) {
        stageA16(0, 0);
    } else if (arok) {
        const float4* p = (const float4*)((const float*)Ap + arowoff + sh);
        float4 f0 = p[0], f1 = p[1], f2 = p[2], f3 = p[3];
        uint4 w0, w1;
        w0.x = pk2(f0.x, f0.y); w0.y = pk2(f0.z, f0.w);
        w0.z = pk2(f1.x, f1.y); w0.w = pk2(f1.z, f1.w);
        w1.x = pk2(f2.x, f2.y); w1.y = pk2(f2.z, f2.w);
        w1.z = pk2(f3.x, f3.y); w1.w = pk2(f3.z, f3.w);
        *(uint4*)&As[0][sr * 32 + sh] = w0;
        *(uint4*)&As[0][sr * 32 + sh + 8] = w1;
    }
    stageB(0, 0);
    __syncthreads();

    int cur = 0;
    for (int kt = 0; kt < NT; ++kt) {
        const int nxt = cur ^ 1;
        const bool more = (kt + 1) < NT;
        float4 f0, f1, f2, f3;
        if (more) {
            const int k0n = (kt + 1) * 32;
            if (ABF16) {
                stageA16(nxt, k0n);
            } else if (arok) {
                const float4* p = (const float4*)((const float*)Ap + arowoff + k0n + sh);
                f0 = p[0]; f1 = p[1]; f2 = p[2]; f3 = p[3];
            }
            stageB(nxt, k0n);
        }

        bf16x8 a[4], b[4];
#pragma unroll
        for (int i = 0; i < 4; i++) a[i] = *(const bf16x8*)&As[cur][(wr + i * 16 + fr) * 32 + kg * 8];
#pragma unroll
        for (int j = 0; j < 4; j++) b[j] = *(const bf16x8*)&Bs[cur][(wc + j * 16 + fr) * 32 + kg * 8];
#pragma unroll
        for (int i = 0; i < 4; i++)
#pragma unroll
            for (int j = 0; j < 4; j++)
                acc[i][j] = __builtin_amdgcn_mfma_f32_16x16x32_bf16(a[i], b[j], acc[i][j], 0, 0, 0);

        if (!ABF16 && more && arok) {
            uint4 w0, w1;
            w0.x = pk2(f0.x, f0.y); w0.y = pk2(f0.z, f0.w);
            w0.z = pk2(f1.x, f1.y); w0.w = pk2(f1.z, f1.w);
            w1.x = pk2(f2.x, f2.y); w1.y = pk2(f2.z, f2.w);
            w1.z = pk2(f3.x, f3.y); w1.w = pk2(f3.z, f3.w);
            *(uint4*)&As[nxt][sr * 32 + sh] = w0;
            *(uint4*)&As[nxt][sr * 32 + sh + 8] = w1;
        }
        __syncthreads();
        cur = nxt;
    }

    const int kg4 = kg * 4;
#pragma unroll
    for (int i = 0; i < 4; i++) {
        const int rb = m0 + wr + i * 16 + kg4;
#pragma unroll
        for (int j = 0; j < 4; j++) {
            const int c = n0 + wc + j * 16 + fr;
#pragma unroll
            for (int r = 0; r < 4; r++) {
                const int row = rb + r;
                if (row < M) {
                    float v = acc[i][j][r] + bias[c];
                    if (EPI == 2) {
                        size_t o = (size_t)row * ldo + c;
                        outf[o] = xres[o] + gelu_(v);
                    } else {
                        outb[(size_t)pose[row] * ldo + c] = f2bf(v);
                    }
                }
            }
        }
    }
}

extern "C" void kernel_launch(void* const* d_in, const int* in_sizes, int n_in,
                              void* d_out, int out_size, void* d_ws, size_t ws_size,
                              hipStream_t stream) {
    const float* x = (const float*)d_in[0];
    const float* ea = (const float*)d_in[1];
    const float* gamma = (const float*)d_in[2];
    const float* beta = (const float*)d_in[3];
    const float* epsp = (const float*)d_in[4];
    const float* W_edge = (const float*)d_in[5];
    const float* b_edge = (const float*)d_in[6];
    const float* W1 = (const float*)d_in[7];
    const float* b1 = (const float*)d_in[8];
    const float* W2 = (const float*)d_in[9];
    const float* b2 = (const float*)d_in[10];
    const int* eidx = (const int*)d_in[11];
    float* out = (float*)d_out;
    const int N = in_sizes[0] / Df;
    const int E = in_sizes[1] / Df;
    const int* esrc = eidx;
    const int* edst = eidx + E;

    char* w = (char*)d_ws;
    size_t off_ = 0;
    auto alloc = [&](size_t bytes) { char* p = w + off_; off_ += (bytes + 255) & ~(size_t)255; return p; };
    float* stats = (float*)alloc(2 * Df * sizeof(float));
    float* coef = (float*)alloc(2 * Df * sizeof(float));
    unsigned short* hb = (unsigned short*)alloc((size_t)N * Df * 2);
    unsigned short* zb = (unsigned short*)alloc((size_t)N * Df * 2);
    unsigned short* tb = (unsigned short*)alloc((size_t)N * Hf * 2);
    unsigned short* WeT = (unsigned short*)alloc((size_t)Df * Df * 2);
    unsigned short* W1T = (unsigned short*)alloc((size_t)Df * Hf * 2);
    unsigned short* W2T = (unsigned short*)alloc((size_t)Hf * Df * 2);
    int* deg = (int*)alloc((size_t)(N + 1) * 4);      // reused as fill cursor
    int* offs = (int*)alloc((size_t)(N + 1) * 4);
    int* srcp = (int*)alloc((size_t)E * 4);
    int* pose = (int*)alloc((size_t)E * 4);
    int* sums = (int*)alloc(64 * 4);
    size_t msgl_bytes = (size_t)E * Df * 2;
    unsigned short* msgl;
    if (off_ + msgl_bytes <= ws_size) msgl = (unsigned short*)alloc(msgl_bytes);
    else msgl = (unsigned short*)d_out;   // dead until final GEMM writes it
    (void)n_in; (void)out_size;

    hipMemsetAsync(stats, 0, 2 * Df * sizeof(float), stream);
    hipMemsetAsync(deg, 0, (size_t)N * 4, stream);

    // BN + h
    bn_stats<<<1024, 192, 0, stream>>>(x, stats, N);
    bn_finalize<<<1, Df, 0, stream>>>(stats, gamma, beta, coef, N);
    int tot8 = N * Df / 8;
    h_kernel<<<(tot8 + 255) / 256, 256, 0, stream>>>(x, coef, hb, tot8);

    // weights (one dispatch)
    wtrans3<<<(Df * Df + 2 * Df * Hf + 255) / 256, 256, 0, stream>>>(
        W_edge, W1, W2, WeT, W1T, W2T);

    // CSR by dst
    int nb = (N + SCAN_CH - 1) / SCAN_CH;
    degree_k<<<(E + 255) / 256, 256, 0, stream>>>(edst, deg, E);
    scan1<<<nb, 256, 0, stream>>>(deg, offs, sums, N);
    scan2<<<1, 1, 0, stream>>>(sums, nb);
    scan3<<<(N + 256) / 256, 256, 0, stream>>>(offs, sums, N, nb);
    hipMemcpyAsync(deg, offs, (size_t)N * 4, hipMemcpyDeviceToDevice, stream);
    fill_k<<<(E + 255) / 256, 256, 0, stream>>>(edst, esrc, deg, srcp, pose, E);

    // edge linear: msgl[pose[e]] = ea[e] @ We^T + b_edge  (f32 A path, bf16 out)
    int ep = (E + 127) / 128;
    gemm_fused<3, false><<<dim3(ep * (Df / 128)), 256, 0, stream>>>(
        ea, WeT, b_edge, E, Df, Df / 128, pose, msgl, nullptr, nullptr, Df);

    // gather-reduce -> z (bf16)
    aggregate<<<2048, 256, 0, stream>>>(msgl, hb, offs, srcp, epsp, zb, N);

    // GEMM1 (strip): tb = bf16(gelu(zb @ W1T^T + b1))
    int strips = (N + 127) / 128;
    gemm_strip<Df, 1><<<dim3(strips * (Hf / 64)), 256, 0, stream>>>(
        zb, W1T, b1, tb, nullptr, nullptr, N, Hf / 64, Hf);

    // GEMM2 (strip, K=768 two halves): out = x + gelu(tb @ W2T^T + b2)
    gemm_strip<Hf, 2><<<dim3(strips * (Df / 64)), 256, 0, stream>>>(
        tb, W2T, b2, nullptr, x, out, N, Df / 64, Df);
}